// Round 1
// baseline (419.983 us; speedup 1.0000x reference)
//
#include <hip/hip_runtime.h>
#include <stdint.h>

typedef unsigned short u16;
typedef __attribute__((ext_vector_type(8))) short bfx8;   // 8 bf16 = 4 VGPR (MFMA A/B frag)
typedef __attribute__((ext_vector_type(4))) float fx4;    // MFMA C/D frag

// ---------- helpers ----------
static __device__ __forceinline__ u16 f2b(float f) {
  union { float f; uint32_t u; } v; v.f = f;
  uint32_t r = v.u + 0x7fffu + ((v.u >> 16) & 1u);   // RNE
  return (u16)(r >> 16);
}

static __device__ __forceinline__ void gload16(const void* g, void* lds) {
  __builtin_amdgcn_global_load_lds((const __attribute__((address_space(1))) uint32_t*)g,
                                   (__attribute__((address_space(3))) uint32_t*)lds,
                                   16, 0, 0);
}

// ---------- f32 -> bf16 convert (8 elems/thread, vectorized) ----------
__global__ __launch_bounds__(256) void f32_to_bf16_k(const float* __restrict__ in,
                                                     u16* __restrict__ out, int n) {
  int i = (blockIdx.x * 256 + threadIdx.x) * 8;
  if (i >= n) return;
  float4 a = *(const float4*)(in + i);
  float4 b = *(const float4*)(in + i + 4);
  bfx8 o;
  o[0]=(short)f2b(a.x); o[1]=(short)f2b(a.y); o[2]=(short)f2b(a.z); o[3]=(short)f2b(a.w);
  o[4]=(short)f2b(b.x); o[5]=(short)f2b(b.y); o[6]=(short)f2b(b.z); o[7]=(short)f2b(b.w);
  *(bfx8*)(out + i) = o;
}

// ---------- 1024x1024 f32 transpose -> bf16 (4 matrices batched in z) ----------
struct TransArgs { const float* in[4]; u16* out[4]; };
__global__ __launch_bounds__(256) void transpose4_k(TransArgs ta) {
  const float* in = ta.in[blockIdx.z];
  u16* out = ta.out[blockIdx.z];
  __shared__ u16 t[64][65];
  const int bx = blockIdx.x * 64, by = blockIdx.y * 64;
  const int tid = threadIdx.x;
#pragma unroll
  for (int i = 0; i < 16; ++i) {
    int idx = tid + i * 256; int r = idx >> 6, c = idx & 63;
    t[c][r] = f2b(in[(size_t)(by + r) * 1024 + bx + c]);
  }
  __syncthreads();
#pragma unroll
  for (int i = 0; i < 16; ++i) {
    int idx = tid + i * 256; int r = idx >> 6, c = idx & 63;
    out[(size_t)(bx + r) * 1024 + by + c] = t[r][c];
  }
}

// ---------- b2[f] = proj_b[f] + sum_e proj_w[f][e]*out_b[e] ----------
__global__ __launch_bounds__(256) void make_b2_k(const float* __restrict__ pw,
                                                 const float* __restrict__ ob,
                                                 const float* __restrict__ pb,
                                                 float* __restrict__ b2) {
  const int f = blockIdx.x, tid = threadIdx.x;
  float s = 0.f;
  for (int e = tid; e < 1024; e += 256) s += pw[(size_t)f * 1024 + e] * ob[e];
#pragma unroll
  for (int d = 1; d < 64; d <<= 1) s += __shfl_xor(s, d);
  __shared__ float red[4];
  if ((tid & 63) == 0) red[tid >> 6] = s;
  __syncthreads();
  if (tid == 0) b2[f] = red[0] + red[1] + red[2] + red[3] + pb[f];
}

// ---------- GEMM core: C = A(MxK) * Bt(NxK)^T, 128x128 tile, BK=64, 4 waves ----------
static __device__ __forceinline__ void gemm_core(const u16* __restrict__ A,
                                                 const u16* __restrict__ Bt,
                                                 int K, int bm, int bn,
                                                 u16* As, u16* Bs, fx4 (&acc)[4][4]) {
  const int tid = threadIdx.x, w = tid >> 6, l = tid & 63, lm = l & 15, lk = l >> 4;
  const int wm = w >> 1, wn = w & 1;
  const int nkt = K >> 6;
  for (int kt = 0; kt < nkt; ++kt) {
#pragma unroll
    for (int i = 0; i < 4; ++i) {
      int off = i * 4096 + w * 1024;         // wave-uniform LDS byte base
      int loff = off + l * 16;               // this lane's byte
      int row = loff >> 7, cb = loff & 127;  // tile row, byte-in-row (BK*2=128B rows)
      gload16((const char*)A + ((size_t)(bm * 128 + row) * K + kt * 64) * 2 + cb,
              (char*)As + off);
      gload16((const char*)Bt + ((size_t)(bn * 128 + row) * K + kt * 64) * 2 + cb,
              (char*)Bs + off);
    }
    __syncthreads();
#pragma unroll
    for (int kk = 0; kk < 2; ++kk) {
      bfx8 a[4], b[4];
#pragma unroll
      for (int mi = 0; mi < 4; ++mi)
        a[mi] = *(const bfx8*)((const char*)As + (wm * 64 + mi * 16 + lm) * 128 + lk * 16 + kk * 64);
#pragma unroll
      for (int nj = 0; nj < 4; ++nj)
        b[nj] = *(const bfx8*)((const char*)Bs + (wn * 64 + nj * 16 + lm) * 128 + lk * 16 + kk * 64);
#pragma unroll
      for (int mi = 0; mi < 4; ++mi)
#pragma unroll
        for (int nj = 0; nj < 4; ++nj)
          acc[mi][nj] = __builtin_amdgcn_mfma_f32_16x16x32_bf16(a[mi], b[nj], acc[mi][nj], 0, 0, 0);
    }
    __syncthreads();
  }
}

// ---------- combine GEMMs (4 batched in z): C[f][d] = sum_e A[f][e]*Bt[d][e], bf16 out ----------
struct CombArgs { const u16* A[4]; const u16* Bt[4]; u16* C[4]; };
__global__ __launch_bounds__(256) void gemm_combine_k(CombArgs ca) {
  const int z = blockIdx.z;
  __shared__ u16 As[8192], Bs[8192];
  fx4 acc[4][4];
#pragma unroll
  for (int mi = 0; mi < 4; ++mi)
#pragma unroll
    for (int nj = 0; nj < 4; ++nj) acc[mi][nj] = 0.f;
  gemm_core(ca.A[z], ca.Bt[z], 1024, blockIdx.x, blockIdx.y, As, Bs, acc);
  const int tid = threadIdx.x, w = tid >> 6, l = tid & 63, lm = l & 15, lk = l >> 4;
  const int wm = w >> 1, wn = w & 1;
  u16* C = ca.C[z];
#pragma unroll
  for (int mi = 0; mi < 4; ++mi)
#pragma unroll
    for (int nj = 0; nj < 4; ++nj)
#pragma unroll
      for (int r = 0; r < 4; ++r) {
        int m = blockIdx.x * 128 + wm * 64 + mi * 16 + lk * 4 + r;
        int n = blockIdx.y * 128 + wn * 64 + nj * 16 + lm;
        C[(size_t)m * 1024 + n] = f2b(acc[mi][nj][r]);
      }
}

// ---------- QKV GEMM: [8192x1024]x[3072x1024]^T + in_b, scatter to (B,H,S,64) bf16 ----------
__global__ __launch_bounds__(256) void gemm_qkv_k(const u16* __restrict__ xb,
                                                  const u16* __restrict__ Wc,
                                                  const float* __restrict__ bias,
                                                  u16* __restrict__ Qh, u16* __restrict__ Kh,
                                                  u16* __restrict__ Vh) {
  __shared__ u16 As[8192], Bs[8192];
  fx4 acc[4][4];
#pragma unroll
  for (int mi = 0; mi < 4; ++mi)
#pragma unroll
    for (int nj = 0; nj < 4; ++nj) acc[mi][nj] = 0.f;
  gemm_core(xb, Wc, 1024, blockIdx.x, blockIdx.y, As, Bs, acc);
  const int tid = threadIdx.x, w = tid >> 6, l = tid & 63, lm = l & 15, lk = l >> 4;
  const int wm = w >> 1, wn = w & 1;
  const int t = (blockIdx.y * 128) >> 10;                    // tensor select (tile-uniform)
  u16* dst = (t == 0) ? Qh : ((t == 1) ? Kh : Vh);
#pragma unroll
  for (int mi = 0; mi < 4; ++mi)
#pragma unroll
    for (int nj = 0; nj < 4; ++nj)
#pragma unroll
      for (int r = 0; r < 4; ++r) {
        int m = blockIdx.x * 128 + wm * 64 + mi * 16 + lk * 4 + r;
        int n = blockIdx.y * 128 + wn * 64 + nj * 16 + lm;
        float v = acc[mi][nj][r] + bias[n];
        int f = n & 1023, h = f >> 6, hd = f & 63, b = m >> 11, s = m & 2047;
        dst[(((size_t)(b * 16 + h)) * 2048 + s) * 64 + hd] = f2b(v);
      }
}

// ---------- final GEMM: ctx[8192x1024] x W2[1024x1024]^T + b2 + x, f32 out ----------
__global__ __launch_bounds__(256) void gemm_final_k(const u16* __restrict__ ctx,
                                                    const u16* __restrict__ W2,
                                                    const float* __restrict__ b2,
                                                    const float* __restrict__ x,
                                                    float* __restrict__ out) {
  __shared__ u16 As[8192], Bs[8192];
  fx4 acc[4][4];
#pragma unroll
  for (int mi = 0; mi < 4; ++mi)
#pragma unroll
    for (int nj = 0; nj < 4; ++nj) acc[mi][nj] = 0.f;
  gemm_core(ctx, W2, 1024, blockIdx.x, blockIdx.y, As, Bs, acc);
  const int tid = threadIdx.x, w = tid >> 6, l = tid & 63, lm = l & 15, lk = l >> 4;
  const int wm = w >> 1, wn = w & 1;
#pragma unroll
  for (int mi = 0; mi < 4; ++mi)
#pragma unroll
    for (int nj = 0; nj < 4; ++nj)
#pragma unroll
      for (int r = 0; r < 4; ++r) {
        int m = blockIdx.x * 128 + wm * 64 + mi * 16 + lk * 4 + r;
        int n = blockIdx.y * 128 + wn * 64 + nj * 16 + lm;
        size_t idx = (size_t)m * 1024 + n;
        out[idx] = acc[mi][nj][r] + b2[n] + x[idx];
      }
}

// ---------- fused attention: scores=QK^T/8 + tril(1.0), softmax over full row, ctx=P*V ----------
// grid: (S/64, B*H); 4 waves/block, 16 q-rows/wave, KV tiles of 64.
// LDS rows are 128B -> XOR-swizzle (byte ^= (row&7)<<4) on K/Vt/P to kill 16-way bank conflicts.
__global__ __launch_bounds__(256) void attn_k(const u16* __restrict__ Qh,
                                              const u16* __restrict__ Kh,
                                              const u16* __restrict__ Vh,
                                              u16* __restrict__ ctx) {
  const int bh = blockIdx.y, qt = blockIdx.x;
  const int tid = threadIdx.x, w = tid >> 6, l = tid & 63, lm = l & 15, lk = l >> 4;
  __shared__ u16 Ks[4096];        // [64 key][64 dim], swizzled
  __shared__ u16 Vt[4096];        // [64 dim][64 key] (transposed), swizzled
  __shared__ u16 Pl[4][1024];     // per-wave P [16 q][64 key], swizzled

  const size_t base = (size_t)bh * 2048 * 64;
  bfx8 qf[2];
  {
    const u16* qp = Qh + base + (size_t)(qt * 64 + w * 16 + lm) * 64;
    qf[0] = *(const bfx8*)(qp + lk * 8);
    qf[1] = *(const bfx8*)(qp + lk * 8 + 32);
  }
  float m_run[4] = {-INFINITY, -INFINITY, -INFINITY, -INFINITY};
  float l_run[4] = {0.f, 0.f, 0.f, 0.f};
  fx4 accO[4];
#pragma unroll
  for (int nj = 0; nj < 4; ++nj) accO[nj] = 0.f;

  const u16* Kb = Kh + base;
  const u16* Vb = Vh + base;
  const int q0 = qt * 64 + w * 16 + lk * 4;

  for (int kt = 0; kt < 32; ++kt) {
    { // stage K tile: contiguous 8KB, swizzled dest
      const uint4* gk = (const uint4*)(Kb + kt * 4096);
      uint4 k0 = gk[tid * 2], k1 = gk[tid * 2 + 1];
      int o = tid * 32, row = o >> 7;
      *(uint4*)((char*)Ks + (o ^ ((row & 7) << 4))) = k0;
      *(uint4*)((char*)Ks + ((o + 16) ^ ((row & 7) << 4))) = k1;
    }
    { // stage V transposed: Vt[hd][k], swizzled
      const u16* gv = Vb + kt * 4096 + (tid >> 2) * 64 + (tid & 3) * 16;
      bfx8 v0 = *(const bfx8*)gv;
      bfx8 v1 = *(const bfx8*)(gv + 8);
      int k = tid >> 2, hdb = (tid & 3) * 16;
#pragma unroll
      for (int e = 0; e < 8; ++e) {
        int hd0 = hdb + e, hd1 = hdb + 8 + e;
        *(u16*)((char*)Vt + ((hd0 * 128 + k * 2) ^ ((hd0 & 7) << 4))) = (u16)v0[e];
        *(u16*)((char*)Vt + ((hd1 * 128 + k * 2) ^ ((hd1 & 7) << 4))) = (u16)v1[e];
      }
    }
    __syncthreads();

    // QK^T -> 16x64 score tile per wave
    fx4 s[4];
#pragma unroll
    for (int nj = 0; nj < 4; ++nj) s[nj] = 0.f;
#pragma unroll
    for (int kk = 0; kk < 2; ++kk)
#pragma unroll
      for (int nj = 0; nj < 4; ++nj) {
        int row = nj * 16 + lm;
        bfx8 kf = *(const bfx8*)((char*)Ks + ((row * 128 + kk * 64 + lk * 16) ^ ((row & 7) << 4)));
        s[nj] = __builtin_amdgcn_mfma_f32_16x16x32_bf16(qf[kk], kf, s[nj], 0, 0, 0);
      }

    // scale + additive tril mask + online softmax (row-reduce across 16-lane group)
    float corr[4];
#pragma unroll
    for (int r = 0; r < 4; ++r) {
      float mx = -INFINITY;
#pragma unroll
      for (int nj = 0; nj < 4; ++nj) {
        int kcol = kt * 64 + nj * 16 + lm;
        float v = s[nj][r] * 0.125f + ((kcol <= q0 + r) ? 1.0f : 0.0f);
        s[nj][r] = v;
        mx = fmaxf(mx, v);
      }
#pragma unroll
      for (int d = 1; d < 16; d <<= 1) mx = fmaxf(mx, __shfl_xor(mx, d));
      float mn = fmaxf(m_run[r], mx);
      corr[r] = __expf(m_run[r] - mn);
      m_run[r] = mn;
      float sum = 0.f;
#pragma unroll
      for (int nj = 0; nj < 4; ++nj) { float p = __expf(s[nj][r] - mn); s[nj][r] = p; sum += p; }
#pragma unroll
      for (int d = 1; d < 16; d <<= 1) sum += __shfl_xor(sum, d);
      l_run[r] = l_run[r] * corr[r] + sum;
    }
#pragma unroll
    for (int nj = 0; nj < 4; ++nj)
#pragma unroll
      for (int r = 0; r < 4; ++r) accO[nj][r] *= corr[r];

    // P -> LDS (bf16, swizzled), then PV MFMAs
#pragma unroll
    for (int nj = 0; nj < 4; ++nj)
#pragma unroll
      for (int r = 0; r < 4; ++r) {
        int row = lk * 4 + r;
        *(u16*)((char*)&Pl[w][0] + ((row * 128 + (nj * 16 + lm) * 2) ^ ((row & 7) << 4))) =
            f2b(s[nj][r]);
      }
#pragma unroll
    for (int kk = 0; kk < 2; ++kk) {
      bfx8 pf = *(const bfx8*)((char*)&Pl[w][0] + ((lm * 128 + kk * 64 + lk * 16) ^ ((lm & 7) << 4)));
#pragma unroll
      for (int nj = 0; nj < 4; ++nj) {
        int row = nj * 16 + lm;
        bfx8 vf = *(const bfx8*)((char*)Vt + ((row * 128 + kk * 64 + lk * 16) ^ ((row & 7) << 4)));
        accO[nj] = __builtin_amdgcn_mfma_f32_16x16x32_bf16(pf, vf, accO[nj], 0, 0, 0);
      }
    }
    __syncthreads();
  }

  // epilogue: ctx (B,S,D) bf16
  const int b = bh >> 4, h = bh & 15;
#pragma unroll
  for (int nj = 0; nj < 4; ++nj)
#pragma unroll
    for (int r = 0; r < 4; ++r) {
      float v = accO[nj][r] / l_run[r];
      int q = q0 + r;
      ctx[((size_t)b * 2048 + q) * 1024 + h * 64 + nj * 16 + lm] = f2b(v);
    }
}

// ---------- launch ----------
extern "C" void kernel_launch(void* const* d_in, const int* in_sizes, int n_in,
                              void* d_out, int out_size, void* d_ws, size_t ws_size,
                              hipStream_t stream) {
  (void)in_sizes; (void)n_in; (void)out_size; (void)ws_size;
  const float* x      = (const float*)d_in[0];
  const float* Wq     = (const float*)d_in[1];
  const float* Wk     = (const float*)d_in[2];
  const float* Wv     = (const float*)d_in[3];
  const float* in_w   = (const float*)d_in[4];
  const float* in_b   = (const float*)d_in[5];
  const float* out_w  = (const float*)d_in[6];
  const float* out_b  = (const float*)d_in[7];
  const float* proj_w = (const float*)d_in[8];
  const float* proj_b = (const float*)d_in[9];
  float* out = (float*)d_out;

  char* ws = (char*)d_ws;
  const size_t MB = 1ull << 20;
  // lifetime-overlapped layout (72 MB + 4 KB total):
  u16* xb   = (u16*)(ws);                    // 16MB; dead after QKV GEMM -> reused as ctx
  u16* ctx  = xb;
  u16* Qh   = (u16*)(ws + 16 * MB);          // 16MB
  u16* Kh   = (u16*)(ws + 32 * MB);          // 16MB; first 6MB doubles as in_w bf16 (prep only)
  u16* Vh   = (u16*)(ws + 48 * MB);          // 16MB; first 8MB = tmpT, +2MB = proj_w bf16 (prep only)
  u16* inwb = Kh;
  u16* tmpT = Vh;
  u16* pwb  = (u16*)(ws + 48 * MB + 8 * MB);
  u16* Wc   = (u16*)(ws + 64 * MB);          // 6MB combined QKV weights
  u16* W2   = (u16*)(ws + 70 * MB);          // 2MB combined output weights
  float* b2 = (float*)(ws + 72 * MB);        // 4KB combined output bias

  f32_to_bf16_k<<<4096, 256, 0, stream>>>(x, xb, 8388608);
  f32_to_bf16_k<<<1536, 256, 0, stream>>>(in_w, inwb, 3145728);
  f32_to_bf16_k<<<512, 256, 0, stream>>>(proj_w, pwb, 1048576);

  TransArgs ta;
  ta.in[0] = Wq; ta.in[1] = Wk; ta.in[2] = Wv; ta.in[3] = out_w;
  for (int z = 0; z < 4; ++z) ta.out[z] = tmpT + (size_t)z * 1048576;
  transpose4_k<<<dim3(16, 16, 4), 256, 0, stream>>>(ta);

  CombArgs ca;
  ca.A[0] = inwb; ca.A[1] = inwb + 1048576; ca.A[2] = inwb + 2097152; ca.A[3] = pwb;
  for (int z = 0; z < 4; ++z) ca.Bt[z] = tmpT + (size_t)z * 1048576;
  ca.C[0] = Wc; ca.C[1] = Wc + 1048576; ca.C[2] = Wc + 2097152; ca.C[3] = W2;
  gemm_combine_k<<<dim3(8, 8, 4), 256, 0, stream>>>(ca);

  make_b2_k<<<1024, 256, 0, stream>>>(proj_w, out_b, proj_b, b2);

  gemm_qkv_k<<<dim3(64, 24), 256, 0, stream>>>(xb, Wc, in_b, Qh, Kh, Vh);
  attn_k<<<dim3(32, 64), 256, 0, stream>>>(Qh, Kh, Vh, ctx);
  gemm_final_k<<<dim3(64, 8), 256, 0, stream>>>(ctx, W2, b2, x, out);
}

// Round 2
// 308.293 us; speedup vs baseline: 1.3623x; 1.3623x over previous
//
#include <hip/hip_runtime.h>
#include <stdint.h>

typedef unsigned short u16;
typedef __attribute__((ext_vector_type(8))) short bfx8;   // 8 bf16 = 4 VGPR (MFMA A/B frag)
typedef __attribute__((ext_vector_type(4))) float fx4;    // MFMA C/D frag
typedef __attribute__((ext_vector_type(2))) unsigned int uint32x2;

// ---------- helpers ----------
static __device__ __forceinline__ u16 f2b(float f) {
  union { float f; uint32_t u; } v; v.f = f;
  uint32_t r = v.u + 0x7fffu + ((v.u >> 16) & 1u);   // RNE
  return (u16)(r >> 16);
}

static __device__ __forceinline__ uint32_t cvtpk(float lo, float hi) {
  uint32_t r;
  asm("v_cvt_pk_bf16_f32 %0, %1, %2" : "=v"(r) : "v"(lo), "v"(hi));
  return r;
}

static __device__ __forceinline__ void gload16(const void* g, void* lds) {
  __builtin_amdgcn_global_load_lds((const __attribute__((address_space(1))) uint32_t*)g,
                                   (__attribute__((address_space(3))) uint32_t*)lds,
                                   16, 0, 0);
}

// ---------- f32 -> bf16 convert (8 elems/thread, vectorized) ----------
__global__ __launch_bounds__(256) void f32_to_bf16_k(const float* __restrict__ in,
                                                     u16* __restrict__ out, int n) {
  int i = (blockIdx.x * 256 + threadIdx.x) * 8;
  if (i >= n) return;
  float4 a = *(const float4*)(in + i);
  float4 b = *(const float4*)(in + i + 4);
  bfx8 o;
  o[0]=(short)f2b(a.x); o[1]=(short)f2b(a.y); o[2]=(short)f2b(a.z); o[3]=(short)f2b(a.w);
  o[4]=(short)f2b(b.x); o[5]=(short)f2b(b.y); o[6]=(short)f2b(b.z); o[7]=(short)f2b(b.w);
  *(bfx8*)(out + i) = o;
}

// ---------- 1024x1024 f32 transpose -> bf16 (4 matrices batched in z) ----------
struct TransArgs { const float* in[4]; u16* out[4]; };
__global__ __launch_bounds__(256) void transpose4_k(TransArgs ta) {
  const float* in = ta.in[blockIdx.z];
  u16* out = ta.out[blockIdx.z];
  __shared__ u16 t[64][65];
  const int bx = blockIdx.x * 64, by = blockIdx.y * 64;
  const int tid = threadIdx.x;
#pragma unroll
  for (int i = 0; i < 16; ++i) {
    int idx = tid + i * 256; int r = idx >> 6, c = idx & 63;
    t[c][r] = f2b(in[(size_t)(by + r) * 1024 + bx + c]);
  }
  __syncthreads();
#pragma unroll
  for (int i = 0; i < 16; ++i) {
    int idx = tid + i * 256; int r = idx >> 6, c = idx & 63;
    out[(size_t)(bx + r) * 1024 + by + c] = t[r][c];
  }
}

// ---------- b2[f] = proj_b[f] + sum_e proj_w[f][e]*out_b[e] ----------
__global__ __launch_bounds__(256) void make_b2_k(const float* __restrict__ pw,
                                                 const float* __restrict__ ob,
                                                 const float* __restrict__ pb,
                                                 float* __restrict__ b2) {
  const int f = blockIdx.x, tid = threadIdx.x;
  float s = 0.f;
  for (int e = tid; e < 1024; e += 256) s += pw[(size_t)f * 1024 + e] * ob[e];
#pragma unroll
  for (int d = 1; d < 64; d <<= 1) s += __shfl_xor(s, d);
  __shared__ float red[4];
  if ((tid & 63) == 0) red[tid >> 6] = s;
  __syncthreads();
  if (tid == 0) b2[f] = red[0] + red[1] + red[2] + red[3] + pb[f];
}

// ---------- GEMM core: C = A(MxK) * Bt(NxK)^T, 128x128 tile, BK=64, 4 waves ----------
static __device__ __forceinline__ void gemm_core(const u16* __restrict__ A,
                                                 const u16* __restrict__ Bt,
                                                 int K, int bm, int bn,
                                                 u16* As, u16* Bs, fx4 (&acc)[4][4]) {
  const int tid = threadIdx.x, w = tid >> 6, l = tid & 63, lm = l & 15, lk = l >> 4;
  const int wm = w >> 1, wn = w & 1;
  const int nkt = K >> 6;
  for (int kt = 0; kt < nkt; ++kt) {
#pragma unroll
    for (int i = 0; i < 4; ++i) {
      int off = i * 4096 + w * 1024;         // wave-uniform LDS byte base
      int loff = off + l * 16;               // this lane's byte
      int row = loff >> 7, cb = loff & 127;  // tile row, byte-in-row (BK*2=128B rows)
      gload16((const char*)A + ((size_t)(bm * 128 + row) * K + kt * 64) * 2 + cb,
              (char*)As + off);
      gload16((const char*)Bt + ((size_t)(bn * 128 + row) * K + kt * 64) * 2 + cb,
              (char*)Bs + off);
    }
    __syncthreads();
#pragma unroll
    for (int kk = 0; kk < 2; ++kk) {
      bfx8 a[4], b[4];
#pragma unroll
      for (int mi = 0; mi < 4; ++mi)
        a[mi] = *(const bfx8*)((const char*)As + (wm * 64 + mi * 16 + lm) * 128 + lk * 16 + kk * 64);
#pragma unroll
      for (int nj = 0; nj < 4; ++nj)
        b[nj] = *(const bfx8*)((const char*)Bs + (wn * 64 + nj * 16 + lm) * 128 + lk * 16 + kk * 64);
#pragma unroll
      for (int mi = 0; mi < 4; ++mi)
#pragma unroll
        for (int nj = 0; nj < 4; ++nj)
          acc[mi][nj] = __builtin_amdgcn_mfma_f32_16x16x32_bf16(a[mi], b[nj], acc[mi][nj], 0, 0, 0);
    }
    __syncthreads();
  }
}

// ---------- combine GEMMs (4 batched in z): C[f][d] = sum_e A[f][e]*Bt[d][e], bf16 out ----------
struct CombArgs { const u16* A[4]; const u16* Bt[4]; u16* C[4]; };
__global__ __launch_bounds__(256) void gemm_combine_k(CombArgs ca) {
  const int z = blockIdx.z;
  __shared__ u16 As[8192], Bs[8192];
  fx4 acc[4][4];
#pragma unroll
  for (int mi = 0; mi < 4; ++mi)
#pragma unroll
    for (int nj = 0; nj < 4; ++nj) acc[mi][nj] = 0.f;
  gemm_core(ca.A[z], ca.Bt[z], 1024, blockIdx.x, blockIdx.y, As, Bs, acc);
  const int tid = threadIdx.x, w = tid >> 6, l = tid & 63, lm = l & 15, lk = l >> 4;
  const int wm = w >> 1, wn = w & 1;
  u16* C = ca.C[z];
#pragma unroll
  for (int mi = 0; mi < 4; ++mi)
#pragma unroll
    for (int nj = 0; nj < 4; ++nj)
#pragma unroll
      for (int r = 0; r < 4; ++r) {
        int m = blockIdx.x * 128 + wm * 64 + mi * 16 + lk * 4 + r;
        int n = blockIdx.y * 128 + wn * 64 + nj * 16 + lm;
        C[(size_t)m * 1024 + n] = f2b(acc[mi][nj][r]);
      }
}

// ---------- QKV GEMM: [8192x1024]x[3072x1024]^T + in_b ----------
// Q -> (B,H,S,64) plain; K -> same but hd XOR-swizzled (attn LDS swizzle baked in);
// V -> per-(bh,ktile) [k/4][d/16][4][16] subtile-permuted (for ds_read_b64_tr_b16).
__global__ __launch_bounds__(256) void gemm_qkv_k(const u16* __restrict__ xb,
                                                  const u16* __restrict__ Wc,
                                                  const float* __restrict__ bias,
                                                  u16* __restrict__ Qh, u16* __restrict__ Kh,
                                                  u16* __restrict__ Vh) {
  __shared__ u16 As[8192], Bs[8192];
  fx4 acc[4][4];
#pragma unroll
  for (int mi = 0; mi < 4; ++mi)
#pragma unroll
    for (int nj = 0; nj < 4; ++nj) acc[mi][nj] = 0.f;
  gemm_core(xb, Wc, 1024, blockIdx.x, blockIdx.y, As, Bs, acc);
  const int tid = threadIdx.x, w = tid >> 6, l = tid & 63, lm = l & 15, lk = l >> 4;
  const int wm = w >> 1, wn = w & 1;
  const int t = (blockIdx.y * 128) >> 10;                    // tensor select (tile-uniform)
  u16* dst = (t == 0) ? Qh : ((t == 1) ? Kh : Vh);
#pragma unroll
  for (int mi = 0; mi < 4; ++mi)
#pragma unroll
    for (int nj = 0; nj < 4; ++nj)
#pragma unroll
      for (int r = 0; r < 4; ++r) {
        int m = blockIdx.x * 128 + wm * 64 + mi * 16 + lk * 4 + r;
        int n = blockIdx.y * 128 + wn * 64 + nj * 16 + lm;
        float v = acc[mi][nj][r] + bias[n];
        int f = n & 1023, h = f >> 6, hd = f & 63, b = m >> 11, s = m & 2047;
        size_t hb = ((size_t)(b * 16 + h)) * 131072;   // 2048*64
        size_t idx;
        if (t == 2) {
          int sl = s & 63, st = s >> 6;
          idx = hb + (size_t)st * 4096 +
                (size_t)((sl >> 2) * 256 + (hd >> 4) * 64 + (sl & 3) * 16 + (hd & 15));
        } else if (t == 1) {
          idx = hb + (size_t)s * 64 + (hd ^ ((s & 7) << 3));
        } else {
          idx = hb + (size_t)s * 64 + hd;
        }
        dst[idx] = f2b(v);
      }
}

// ---------- final GEMM: ctx[8192x1024] x W2[1024x1024]^T + b2 + x, f32 out ----------
__global__ __launch_bounds__(256) void gemm_final_k(const u16* __restrict__ ctx,
                                                    const u16* __restrict__ W2,
                                                    const float* __restrict__ b2,
                                                    const float* __restrict__ x,
                                                    float* __restrict__ out) {
  __shared__ u16 As[8192], Bs[8192];
  fx4 acc[4][4];
#pragma unroll
  for (int mi = 0; mi < 4; ++mi)
#pragma unroll
    for (int nj = 0; nj < 4; ++nj) acc[mi][nj] = 0.f;
  gemm_core(ctx, W2, 1024, blockIdx.x, blockIdx.y, As, Bs, acc);
  const int tid = threadIdx.x, w = tid >> 6, l = tid & 63, lm = l & 15, lk = l >> 4;
  const int wm = w >> 1, wn = w & 1;
#pragma unroll
  for (int mi = 0; mi < 4; ++mi)
#pragma unroll
    for (int nj = 0; nj < 4; ++nj)
#pragma unroll
      for (int r = 0; r < 4; ++r) {
        int m = blockIdx.x * 128 + wm * 64 + mi * 16 + lk * 4 + r;
        int n = blockIdx.y * 128 + wn * 64 + nj * 16 + lm;
        size_t idx = (size_t)m * 1024 + n;
        out[idx] = acc[mi][nj][r] + b2[n] + x[idx];
      }
}

// ---------- fused attention (rewritten) ----------
// scores = QK^T/8 + tril(1.0), softmax over FULL row, ctx = P*V.
// grid: (S/64, B*H); 4 waves/block, 16 q-rows/wave, KV tiles of 64, double-buffered.
// Swapped QK^T: S^T = mfma(K, Q) -> lane owns one q-row (q = lm); softmax nearly lane-local.
// K staged linearly from pre-swizzled global; V staged linearly from subtile-permuted
// global and consumed via ds_read_b64_tr_b16 (HW transpose).
#define TRRD(d, IMM) asm volatile("ds_read_b64_tr_b16 %0, %1 offset:" IMM : "=v"(d) : "v"(va))

__global__ __launch_bounds__(256) void attn_k(const u16* __restrict__ Qh,
                                              const u16* __restrict__ Kh,
                                              const u16* __restrict__ Vh,
                                              u16* __restrict__ ctx) {
  const int bh = blockIdx.y, qt = blockIdx.x;
  const int tid = threadIdx.x, w = tid >> 6, l = tid & 63, lm = l & 15, lk = l >> 4;
  __shared__ __align__(16) u16 Ks[2][4096];
  __shared__ __align__(16) u16 Vs[2][4096];
  __shared__ __align__(16) u16 Pl[4][1024];

  const size_t base = (size_t)bh * 131072;
  bfx8 qf[2];
  {
    const u16* qp = Qh + base + (size_t)(qt * 64 + w * 16 + lm) * 64;
    qf[0] = *(const bfx8*)(qp + lk * 8);
    qf[1] = *(const bfx8*)(qp + lk * 8 + 32);
  }
  float m_run = -INFINITY, l_part = 0.f;
  fx4 accO[4];
#pragma unroll
  for (int nj = 0; nj < 4; ++nj) accO[nj] = 0.f;

  const char* Kg = (const char*)(Kh + base);
  const char* Vg = (const char*)(Vh + base);
  const int o0 = w * 1024 + l * 16, o1 = o0 + 4096;

  const int swz = (lm & 7) << 4;
  const uint32_t vs_base =
      (uint32_t)(uintptr_t)(__attribute__((address_space(3))) char*)&Vs[0][0];
  const uint32_t vtrb = vs_base + (uint32_t)(lk * 1024 + lm * 8);

  // prologue stage tile 0
  gload16(Kg + o0, (char*)Ks[0] + o0);
  gload16(Kg + o1, (char*)Ks[0] + o1);
  gload16(Vg + o0, (char*)Vs[0] + o0);
  gload16(Vg + o1, (char*)Vs[0] + o1);
  __syncthreads();

  const int qg = qt * 64 + w * 16 + lm;   // this lane's q row (global)
  int cur = 0;
  for (int kt = 0; kt < 32; ++kt) {
    if (kt < 31) {  // prefetch next tile into other buffer
      int nb = cur ^ 1;
      const char* kg = Kg + (kt + 1) * 8192;
      const char* vg = Vg + (kt + 1) * 8192;
      gload16(kg + o0, (char*)Ks[nb] + o0);
      gload16(kg + o1, (char*)Ks[nb] + o1);
      gload16(vg + o0, (char*)Vs[nb] + o0);
      gload16(vg + o1, (char*)Vs[nb] + o1);
    }
    const char* Kc = (const char*)Ks[cur];
    // QK^T (swapped): S^T tile, lane holds keys nj*16+lk*4+r for q=lm
    fx4 s[4];
#pragma unroll
    for (int nj = 0; nj < 4; ++nj) s[nj] = 0.f;
#pragma unroll
    for (int kk = 0; kk < 2; ++kk)
#pragma unroll
      for (int nj = 0; nj < 4; ++nj) {
        bfx8 kf = *(const bfx8*)(Kc + nj * 2048 + lm * 128 +
                                 (((kk * 4 + lk) ^ (lm & 7)) << 4));
        s[nj] = __builtin_amdgcn_mfma_f32_16x16x32_bf16(kf, qf[kk], s[nj], 0, 0, 0);
      }
    // scale + additive tril mask (tile-uniform except diagonal tile)
    if (kt < qt) {
#pragma unroll
      for (int nj = 0; nj < 4; ++nj)
#pragma unroll
        for (int r = 0; r < 4; ++r) s[nj][r] = fmaf(s[nj][r], 0.125f, 1.0f);
    } else if (kt > qt) {
#pragma unroll
      for (int nj = 0; nj < 4; ++nj)
#pragma unroll
        for (int r = 0; r < 4; ++r) s[nj][r] *= 0.125f;
    } else {
#pragma unroll
      for (int nj = 0; nj < 4; ++nj)
#pragma unroll
        for (int r = 0; r < 4; ++r) {
          int key = kt * 64 + nj * 16 + lk * 4 + r;
          s[nj][r] = s[nj][r] * 0.125f + ((key <= qg) ? 1.0f : 0.0f);
        }
    }
    // online softmax, defer-max (THR=8)
    float mx = fmaxf(fmaxf(fmaxf(s[0][0], s[0][1]), fmaxf(s[0][2], s[0][3])),
                     fmaxf(fmaxf(s[1][0], s[1][1]), fmaxf(s[1][2], s[1][3])));
    mx = fmaxf(mx, fmaxf(fmaxf(fmaxf(s[2][0], s[2][1]), fmaxf(s[2][2], s[2][3])),
                         fmaxf(fmaxf(s[3][0], s[3][1]), fmaxf(s[3][2], s[3][3]))));
    if (!__all(mx <= m_run + 8.0f)) {
      mx = fmaxf(mx, __shfl_xor(mx, 16));
      mx = fmaxf(mx, __shfl_xor(mx, 32));
      float mn = fmaxf(m_run, mx);
      float corr = __expf(m_run - mn);
      m_run = mn;
      l_part *= corr;
#pragma unroll
      for (int r = 0; r < 4; ++r) {
        float cr = __shfl(corr, (l & 48) | (lk * 4 + r));
#pragma unroll
        for (int nj = 0; nj < 4; ++nj) accO[nj][r] *= cr;
      }
    }
    float lsum = 0.f;
#pragma unroll
    for (int nj = 0; nj < 4; ++nj)
#pragma unroll
      for (int r = 0; r < 4; ++r) {
        float p = __expf(s[nj][r] - m_run);
        s[nj][r] = p;
        lsum += p;
      }
    l_part += lsum;
    // P -> LDS: cvt_pk pairs, 4x ds_write_b64 (row q=lm, keys nj*16+lk*4+0..3)
#pragma unroll
    for (int nj = 0; nj < 4; ++nj) {
      uint32x2 pw;
      pw[0] = cvtpk(s[nj][0], s[nj][1]);
      pw[1] = cvtpk(s[nj][2], s[nj][3]);
      *(uint32x2*)((char*)Pl[w] + ((lm * 128 + nj * 32 + lk * 8) ^ swz)) = pw;
    }
    // V fragments via hardware transpose read (issue all 16, then wait once)
    uint32x2 tr[2][4][2];
    uint32_t va = vtrb + (uint32_t)(cur * 8192);
    TRRD(tr[0][0][0], "0");    TRRD(tr[0][0][1], "512");
    TRRD(tr[0][1][0], "128");  TRRD(tr[0][1][1], "640");
    TRRD(tr[0][2][0], "256");  TRRD(tr[0][2][1], "768");
    TRRD(tr[0][3][0], "384");  TRRD(tr[0][3][1], "896");
    TRRD(tr[1][0][0], "4096"); TRRD(tr[1][0][1], "4608");
    TRRD(tr[1][1][0], "4224"); TRRD(tr[1][1][1], "4736");
    TRRD(tr[1][2][0], "4352"); TRRD(tr[1][2][1], "4864");
    TRRD(tr[1][3][0], "4480"); TRRD(tr[1][3][1], "4992");
    asm volatile("s_waitcnt lgkmcnt(0)" ::: "memory");
    __builtin_amdgcn_sched_barrier(0);
    // PV
#pragma unroll
    for (int kk = 0; kk < 2; ++kk) {
      bfx8 pf = *(const bfx8*)((char*)Pl[w] + ((lm * 128 + kk * 64 + lk * 16) ^ swz));
#pragma unroll
      for (int nj = 0; nj < 4; ++nj) {
        union { uint32x2 u2[2]; bfx8 v; } u;
        u.u2[0] = tr[kk][nj][0];
        u.u2[1] = tr[kk][nj][1];
        accO[nj] = __builtin_amdgcn_mfma_f32_16x16x32_bf16(pf, u.v, accO[nj], 0, 0, 0);
      }
    }
    __syncthreads();
    cur ^= 1;
  }

  // epilogue: reduce l across the 4 lanes sharing each q, write ctx (B,S,D) bf16
  float lt = l_part;
  lt += __shfl_xor(lt, 16);
  lt += __shfl_xor(lt, 32);
  const int b = bh >> 4, h = bh & 15;
#pragma unroll
  for (int r = 0; r < 4; ++r) {
    float li = __shfl(lt, (l & 48) | (lk * 4 + r));
    float inv = 1.0f / li;
    int q = qt * 64 + w * 16 + lk * 4 + r;
#pragma unroll
    for (int nj = 0; nj < 4; ++nj)
      ctx[((size_t)b * 2048 + q) * 1024 + h * 64 + nj * 16 + lm] = f2b(accO[nj][r] * inv);
  }
}

// ---------- launch ----------
extern "C" void kernel_launch(void* const* d_in, const int* in_sizes, int n_in,
                              void* d_out, int out_size, void* d_ws, size_t ws_size,
                              hipStream_t stream) {
  (void)in_sizes; (void)n_in; (void)out_size; (void)ws_size;
  const float* x      = (const float*)d_in[0];
  const float* Wq     = (const float*)d_in[1];
  const float* Wk     = (const float*)d_in[2];
  const float* Wv     = (const float*)d_in[3];
  const float* in_w   = (const float*)d_in[4];
  const float* in_b   = (const float*)d_in[5];
  const float* out_w  = (const float*)d_in[6];
  const float* out_b  = (const float*)d_in[7];
  const float* proj_w = (const float*)d_in[8];
  const float* proj_b = (const float*)d_in[9];
  float* out = (float*)d_out;

  char* ws = (char*)d_ws;
  const size_t MB = 1ull << 20;
  // lifetime-overlapped layout (72 MB + 4 KB total):
  u16* xb   = (u16*)(ws);                    // 16MB; dead after QKV GEMM -> reused as ctx
  u16* ctx  = xb;
  u16* Qh   = (u16*)(ws + 16 * MB);          // 16MB
  u16* Kh   = (u16*)(ws + 32 * MB);          // 16MB; first 6MB doubles as in_w bf16 (prep only)
  u16* Vh   = (u16*)(ws + 48 * MB);          // 16MB; first 8MB = tmpT, +2MB = proj_w bf16 (prep only)
  u16* inwb = Kh;
  u16* tmpT = Vh;
  u16* pwb  = (u16*)(ws + 48 * MB + 8 * MB);
  u16* Wc   = (u16*)(ws + 64 * MB);          // 6MB combined QKV weights
  u16* W2   = (u16*)(ws + 70 * MB);          // 2MB combined output weights
  float* b2 = (float*)(ws + 72 * MB);        // 4KB combined output bias

  f32_to_bf16_k<<<4096, 256, 0, stream>>>(x, xb, 8388608);
  f32_to_bf16_k<<<1536, 256, 0, stream>>>(in_w, inwb, 3145728);
  f32_to_bf16_k<<<512, 256, 0, stream>>>(proj_w, pwb, 1048576);

  TransArgs ta;
  ta.in[0] = Wq; ta.in[1] = Wk; ta.in[2] = Wv; ta.in[3] = out_w;
  for (int z = 0; z < 4; ++z) ta.out[z] = tmpT + (size_t)z * 1048576;
  transpose4_k<<<dim3(16, 16, 4), 256, 0, stream>>>(ta);

  CombArgs ca;
  ca.A[0] = inwb; ca.A[1] = inwb + 1048576; ca.A[2] = inwb + 2097152; ca.A[3] = pwb;
  for (int z = 0; z < 4; ++z) ca.Bt[z] = tmpT + (size_t)z * 1048576;
  ca.C[0] = Wc; ca.C[1] = Wc + 1048576; ca.C[2] = Wc + 2097152; ca.C[3] = W2;
  gemm_combine_k<<<dim3(8, 8, 4), 256, 0, stream>>>(ca);

  make_b2_k<<<1024, 256, 0, stream>>>(proj_w, out_b, proj_b, b2);

  gemm_qkv_k<<<dim3(64, 24), 256, 0, stream>>>(xb, Wc, in_b, Qh, Kh, Vh);
  attn_k<<<dim3(32, 64), 256, 0, stream>>>(Qh, Kh, Vh, ctx);
  gemm_final_k<<<dim3(64, 8), 256, 0, stream>>>(ctx, W2, b2, x, out);
}

// Round 3
// 299.295 us; speedup vs baseline: 1.4032x; 1.0301x over previous
//
#include <hip/hip_runtime.h>
#include <stdint.h>

typedef unsigned short u16;
typedef __attribute__((ext_vector_type(8))) short bfx8;   // 8 bf16 = 4 VGPR (MFMA A/B frag)
typedef __attribute__((ext_vector_type(4))) float fx4;    // MFMA C/D frag
typedef __attribute__((ext_vector_type(2))) unsigned int uint32x2;

// ---------- helpers ----------
static __device__ __forceinline__ u16 f2b(float f) {
  union { float f; uint32_t u; } v; v.f = f;
  uint32_t r = v.u + 0x7fffu + ((v.u >> 16) & 1u);   // RNE
  return (u16)(r >> 16);
}

static __device__ __forceinline__ uint32_t cvtpk(float lo, float hi) {
  uint32_t r;
  asm("v_cvt_pk_bf16_f32 %0, %1, %2" : "=v"(r) : "v"(lo), "v"(hi));
  return r;
}

static __device__ __forceinline__ float ex2(float x) {   // raw v_exp_f32 (2^x)
  float r;
  asm("v_exp_f32 %0, %1" : "=v"(r) : "v"(x));
  return r;
}

static __device__ __forceinline__ void gload16(const void* g, void* lds) {
  __builtin_amdgcn_global_load_lds((const __attribute__((address_space(1))) uint32_t*)g,
                                   (__attribute__((address_space(3))) uint32_t*)lds,
                                   16, 0, 0);
}

// ---------- f32 -> bf16 convert (8 elems/thread, vectorized) ----------
__global__ __launch_bounds__(256) void f32_to_bf16_k(const float* __restrict__ in,
                                                     u16* __restrict__ out, int n) {
  int i = (blockIdx.x * 256 + threadIdx.x) * 8;
  if (i >= n) return;
  float4 a = *(const float4*)(in + i);
  float4 b = *(const float4*)(in + i + 4);
  bfx8 o;
  o[0]=(short)f2b(a.x); o[1]=(short)f2b(a.y); o[2]=(short)f2b(a.z); o[3]=(short)f2b(a.w);
  o[4]=(short)f2b(b.x); o[5]=(short)f2b(b.y); o[6]=(short)f2b(b.z); o[7]=(short)f2b(b.w);
  *(bfx8*)(out + i) = o;
}

// ---------- 1024x1024 f32 transpose -> bf16 (4 matrices batched in z) ----------
struct TransArgs { const float* in[4]; u16* out[4]; };
__global__ __launch_bounds__(256) void transpose4_k(TransArgs ta) {
  const float* in = ta.in[blockIdx.z];
  u16* out = ta.out[blockIdx.z];
  __shared__ u16 t[64][65];
  const int bx = blockIdx.x * 64, by = blockIdx.y * 64;
  const int tid = threadIdx.x;
#pragma unroll
  for (int i = 0; i < 16; ++i) {
    int idx = tid + i * 256; int r = idx >> 6, c = idx & 63;
    t[c][r] = f2b(in[(size_t)(by + r) * 1024 + bx + c]);
  }
  __syncthreads();
#pragma unroll
  for (int i = 0; i < 16; ++i) {
    int idx = tid + i * 256; int r = idx >> 6, c = idx & 63;
    out[(size_t)(bx + r) * 1024 + by + c] = t[r][c];
  }
}

// ---------- b2[f] = proj_b[f] + sum_e proj_w[f][e]*out_b[e] ----------
__global__ __launch_bounds__(256) void make_b2_k(const float* __restrict__ pw,
                                                 const float* __restrict__ ob,
                                                 const float* __restrict__ pb,
                                                 float* __restrict__ b2) {
  const int f = blockIdx.x, tid = threadIdx.x;
  float s = 0.f;
  for (int e = tid; e < 1024; e += 256) s += pw[(size_t)f * 1024 + e] * ob[e];
#pragma unroll
  for (int d = 1; d < 64; d <<= 1) s += __shfl_xor(s, d);
  __shared__ float red[4];
  if ((tid & 63) == 0) red[tid >> 6] = s;
  __syncthreads();
  if (tid == 0) b2[f] = red[0] + red[1] + red[2] + red[3] + pb[f];
}

// ---------- GEMM core: C = A(MxK) * Bt(NxK)^T, 128x128 tile, BK=64, 4 waves ----------
static __device__ __forceinline__ void gemm_core(const u16* __restrict__ A,
                                                 const u16* __restrict__ Bt,
                                                 int K, int bm, int bn,
                                                 u16* As, u16* Bs, fx4 (&acc)[4][4]) {
  const int tid = threadIdx.x, w = tid >> 6, l = tid & 63, lm = l & 15, lk = l >> 4;
  const int wm = w >> 1, wn = w & 1;
  const int nkt = K >> 6;
  for (int kt = 0; kt < nkt; ++kt) {
#pragma unroll
    for (int i = 0; i < 4; ++i) {
      int off = i * 4096 + w * 1024;         // wave-uniform LDS byte base
      int loff = off + l * 16;               // this lane's byte
      int row = loff >> 7, cb = loff & 127;  // tile row, byte-in-row (BK*2=128B rows)
      gload16((const char*)A + ((size_t)(bm * 128 + row) * K + kt * 64) * 2 + cb,
              (char*)As + off);
      gload16((const char*)Bt + ((size_t)(bn * 128 + row) * K + kt * 64) * 2 + cb,
              (char*)Bs + off);
    }
    __syncthreads();
#pragma unroll
    for (int kk = 0; kk < 2; ++kk) {
      bfx8 a[4], b[4];
#pragma unroll
      for (int mi = 0; mi < 4; ++mi)
        a[mi] = *(const bfx8*)((const char*)As + (wm * 64 + mi * 16 + lm) * 128 + lk * 16 + kk * 64);
#pragma unroll
      for (int nj = 0; nj < 4; ++nj)
        b[nj] = *(const bfx8*)((const char*)Bs + (wn * 64 + nj * 16 + lm) * 128 + lk * 16 + kk * 64);
#pragma unroll
      for (int mi = 0; mi < 4; ++mi)
#pragma unroll
        for (int nj = 0; nj < 4; ++nj)
          acc[mi][nj] = __builtin_amdgcn_mfma_f32_16x16x32_bf16(a[mi], b[nj], acc[mi][nj], 0, 0, 0);
    }
    __syncthreads();
  }
}

// ---------- combine GEMMs (4 batched in z): C[f][d] = sum_e A[f][e]*Bt[d][e], bf16 out ----------
struct CombArgs { const u16* A[4]; const u16* Bt[4]; u16* C[4]; };
__global__ __launch_bounds__(256) void gemm_combine_k(CombArgs ca) {
  const int z = blockIdx.z;
  __shared__ u16 As[8192], Bs[8192];
  fx4 acc[4][4];
#pragma unroll
  for (int mi = 0; mi < 4; ++mi)
#pragma unroll
    for (int nj = 0; nj < 4; ++nj) acc[mi][nj] = 0.f;
  gemm_core(ca.A[z], ca.Bt[z], 1024, blockIdx.x, blockIdx.y, As, Bs, acc);
  const int tid = threadIdx.x, w = tid >> 6, l = tid & 63, lm = l & 15, lk = l >> 4;
  const int wm = w >> 1, wn = w & 1;
  u16* C = ca.C[z];
#pragma unroll
  for (int mi = 0; mi < 4; ++mi)
#pragma unroll
    for (int nj = 0; nj < 4; ++nj)
#pragma unroll
      for (int r = 0; r < 4; ++r) {
        int m = blockIdx.x * 128 + wm * 64 + mi * 16 + lk * 4 + r;
        int n = blockIdx.y * 128 + wn * 64 + nj * 16 + lm;
        C[(size_t)m * 1024 + n] = f2b(acc[mi][nj][r]);
      }
}

// ---------- QKV GEMM: [8192x1024]x[3072x1024]^T + in_b ----------
// Q -> (B,H,S,64) plain; K -> same but hd XOR-swizzled (attn LDS swizzle baked in);
// V -> per-(bh,ktile) [k/4][d/16][4][16] subtile-permuted (for ds_read_b64_tr_b16).
__global__ __launch_bounds__(256) void gemm_qkv_k(const u16* __restrict__ xb,
                                                  const u16* __restrict__ Wc,
                                                  const float* __restrict__ bias,
                                                  u16* __restrict__ Qh, u16* __restrict__ Kh,
                                                  u16* __restrict__ Vh) {
  __shared__ u16 As[8192], Bs[8192];
  fx4 acc[4][4];
#pragma unroll
  for (int mi = 0; mi < 4; ++mi)
#pragma unroll
    for (int nj = 0; nj < 4; ++nj) acc[mi][nj] = 0.f;
  gemm_core(xb, Wc, 1024, blockIdx.x, blockIdx.y, As, Bs, acc);
  const int tid = threadIdx.x, w = tid >> 6, l = tid & 63, lm = l & 15, lk = l >> 4;
  const int wm = w >> 1, wn = w & 1;
  const int t = (blockIdx.y * 128) >> 10;                    // tensor select (tile-uniform)
  u16* dst = (t == 0) ? Qh : ((t == 1) ? Kh : Vh);
#pragma unroll
  for (int mi = 0; mi < 4; ++mi)
#pragma unroll
    for (int nj = 0; nj < 4; ++nj)
#pragma unroll
      for (int r = 0; r < 4; ++r) {
        int m = blockIdx.x * 128 + wm * 64 + mi * 16 + lk * 4 + r;
        int n = blockIdx.y * 128 + wn * 64 + nj * 16 + lm;
        float v = acc[mi][nj][r] + bias[n];
        int f = n & 1023, h = f >> 6, hd = f & 63, b = m >> 11, s = m & 2047;
        size_t hb = ((size_t)(b * 16 + h)) * 131072;   // 2048*64
        size_t idx;
        if (t == 2) {
          int sl = s & 63, st = s >> 6;
          idx = hb + (size_t)st * 4096 +
                (size_t)((sl >> 2) * 256 + (hd >> 4) * 64 + (sl & 3) * 16 + (hd & 15));
        } else if (t == 1) {
          idx = hb + (size_t)s * 64 + (hd ^ ((s & 7) << 3));
        } else {
          idx = hb + (size_t)s * 64 + hd;
        }
        dst[idx] = f2b(v);
      }
}

// ---------- final GEMM: ctx[8192x1024] x W2[1024x1024]^T + b2 + x, f32 out ----------
__global__ __launch_bounds__(256) void gemm_final_k(const u16* __restrict__ ctx,
                                                    const u16* __restrict__ W2,
                                                    const float* __restrict__ b2,
                                                    const float* __restrict__ x,
                                                    float* __restrict__ out) {
  __shared__ u16 As[8192], Bs[8192];
  fx4 acc[4][4];
#pragma unroll
  for (int mi = 0; mi < 4; ++mi)
#pragma unroll
    for (int nj = 0; nj < 4; ++nj) acc[mi][nj] = 0.f;
  gemm_core(ctx, W2, 1024, blockIdx.x, blockIdx.y, As, Bs, acc);
  const int tid = threadIdx.x, w = tid >> 6, l = tid & 63, lm = l & 15, lk = l >> 4;
  const int wm = w >> 1, wn = w & 1;
#pragma unroll
  for (int mi = 0; mi < 4; ++mi)
#pragma unroll
    for (int nj = 0; nj < 4; ++nj)
#pragma unroll
      for (int r = 0; r < 4; ++r) {
        int m = blockIdx.x * 128 + wm * 64 + mi * 16 + lk * 4 + r;
        int n = blockIdx.y * 128 + wn * 64 + nj * 16 + lm;
        size_t idx = (size_t)m * 1024 + n;
        out[idx] = acc[mi][nj][r] + b2[n] + x[idx];
      }
}

// ---------- fused attention ----------
// scores = QK^T/8 + tril(1.0), softmax over FULL row (in log2 domain), ctx = P*V.
// QBLK=128: grid (S/128, B*H); 4 waves/block; each wave owns 2 q-groups of 16 rows.
// K-frags / V tr-frags / staging shared across both groups (2x work per LDS byte).
// Swapped QK^T: S^T = mfma(K, Q) -> lane owns one q-row per group (q = lm).
#define TRRD(d, IMM) asm volatile("ds_read_b64_tr_b16 %0, %1 offset:" IMM : "=v"(d) : "v"(va))

__global__ __launch_bounds__(256) void attn_k(const u16* __restrict__ Qh,
                                              const u16* __restrict__ Kh,
                                              const u16* __restrict__ Vh,
                                              u16* __restrict__ ctx) {
  const int bh = blockIdx.y, qt = blockIdx.x;
  const int tid = threadIdx.x, w = tid >> 6, l = tid & 63, lm = l & 15, lk = l >> 4;
  __shared__ __align__(16) u16 Ks[2][4096];
  __shared__ __align__(16) u16 Vs[2][4096];
  __shared__ __align__(16) u16 Pl[4][1024];

  const float SC = 0.18033688011112042f;    // 0.125 * log2(e)
  const float MA = 1.4426950408889634f;     // 1.0  * log2(e)
  const float THR = 11.541560327111708f;    // 8.0  * log2(e)

  const size_t base = (size_t)bh * 131072;
  bfx8 qf[2][2];
#pragma unroll
  for (int g = 0; g < 2; ++g) {
    const u16* qp = Qh + base + (size_t)(qt * 128 + g * 64 + w * 16 + lm) * 64;
    qf[g][0] = *(const bfx8*)(qp + lk * 8);
    qf[g][1] = *(const bfx8*)(qp + lk * 8 + 32);
  }
  float m_run[2] = {-INFINITY, -INFINITY};
  float l_part[2] = {0.f, 0.f};
  fx4 accO[2][4];
#pragma unroll
  for (int g = 0; g < 2; ++g)
#pragma unroll
    for (int nj = 0; nj < 4; ++nj) accO[g][nj] = 0.f;

  const char* Kg = (const char*)(Kh + base);
  const char* Vg = (const char*)(Vh + base);
  const int o0 = w * 1024 + l * 16, o1 = o0 + 4096;

  const int swz = (lm & 7) << 4;
  const uint32_t vs_base =
      (uint32_t)(uintptr_t)(__attribute__((address_space(3))) char*)&Vs[0][0];
  const uint32_t vtrb = vs_base + (uint32_t)(lk * 1024 + lm * 8);

  // prologue stage tile 0
  gload16(Kg + o0, (char*)Ks[0] + o0);
  gload16(Kg + o1, (char*)Ks[0] + o1);
  gload16(Vg + o0, (char*)Vs[0] + o0);
  gload16(Vg + o1, (char*)Vs[0] + o1);
  __syncthreads();

  int cur = 0;
  for (int kt = 0; kt < 32; ++kt) {
    if (kt < 31) {  // prefetch next tile into other buffer
      int nb = cur ^ 1;
      const char* kg = Kg + (kt + 1) * 8192;
      const char* vg = Vg + (kt + 1) * 8192;
      gload16(kg + o0, (char*)Ks[nb] + o0);
      gload16(kg + o1, (char*)Ks[nb] + o1);
      gload16(vg + o0, (char*)Vs[nb] + o0);
      gload16(vg + o1, (char*)Vs[nb] + o1);
    }
    const char* Kc = (const char*)Ks[cur];
    // QK^T (swapped): per group, lane holds keys nj*16+lk*4+r for q = lm
    fx4 s[2][4];
#pragma unroll
    for (int g = 0; g < 2; ++g)
#pragma unroll
      for (int nj = 0; nj < 4; ++nj) s[g][nj] = 0.f;
#pragma unroll
    for (int kk = 0; kk < 2; ++kk) {
      bfx8 kf[4];
#pragma unroll
      for (int nj = 0; nj < 4; ++nj)
        kf[nj] = *(const bfx8*)(Kc + nj * 2048 + lm * 128 +
                                (((kk * 4 + lk) ^ (lm & 7)) << 4));
#pragma unroll
      for (int g = 0; g < 2; ++g)
#pragma unroll
        for (int nj = 0; nj < 4; ++nj)
          s[g][nj] = __builtin_amdgcn_mfma_f32_16x16x32_bf16(kf[nj], qf[g][kk], s[g][nj], 0, 0, 0);
    }
    // scale to log2 domain + additive tril mask (tile-uniform except diagonal tile)
#pragma unroll
    for (int g = 0; g < 2; ++g) {
      const int dk = kt - 2 * qt - g;
      if (dk < 0) {
#pragma unroll
        for (int nj = 0; nj < 4; ++nj)
#pragma unroll
          for (int r = 0; r < 4; ++r) s[g][nj][r] = fmaf(s[g][nj][r], SC, MA);
      } else if (dk > 0) {
#pragma unroll
        for (int nj = 0; nj < 4; ++nj)
#pragma unroll
          for (int r = 0; r < 4; ++r) s[g][nj][r] *= SC;
      } else {
        const int qg = qt * 128 + g * 64 + w * 16 + lm;
#pragma unroll
        for (int nj = 0; nj < 4; ++nj)
#pragma unroll
          for (int r = 0; r < 4; ++r) {
            int key = kt * 64 + nj * 16 + lk * 4 + r;
            s[g][nj][r] = s[g][nj][r] * SC + ((key <= qg) ? MA : 0.0f);
          }
      }
      // online softmax in log2 domain, defer-max
      float mx = fmaxf(fmaxf(fmaxf(s[g][0][0], s[g][0][1]), fmaxf(s[g][0][2], s[g][0][3])),
                       fmaxf(fmaxf(s[g][1][0], s[g][1][1]), fmaxf(s[g][1][2], s[g][1][3])));
      mx = fmaxf(mx, fmaxf(fmaxf(fmaxf(s[g][2][0], s[g][2][1]), fmaxf(s[g][2][2], s[g][2][3])),
                           fmaxf(fmaxf(s[g][3][0], s[g][3][1]), fmaxf(s[g][3][2], s[g][3][3]))));
      if (!__all(mx <= m_run[g] + THR)) {
        mx = fmaxf(mx, __shfl_xor(mx, 16));
        mx = fmaxf(mx, __shfl_xor(mx, 32));
        float mn = fmaxf(m_run[g], mx);
        float corr = ex2(m_run[g] - mn);
        m_run[g] = mn;
        l_part[g] *= corr;
#pragma unroll
        for (int r = 0; r < 4; ++r) {
          float cr = __shfl(corr, (l & 48) | (lk * 4 + r));
#pragma unroll
          for (int nj = 0; nj < 4; ++nj) accO[g][nj][r] *= cr;
        }
      }
      float lsum = 0.f;
#pragma unroll
      for (int nj = 0; nj < 4; ++nj)
#pragma unroll
        for (int r = 0; r < 4; ++r) {
          float p = ex2(s[g][nj][r] - m_run[g]);
          s[g][nj][r] = p;
          lsum += p;
        }
      l_part[g] += lsum;
    }
    // group 0: P -> LDS (cvt_pk pairs, 4x ds_write_b64)
#pragma unroll
    for (int nj = 0; nj < 4; ++nj) {
      uint32x2 pw;
      pw[0] = cvtpk(s[0][nj][0], s[0][nj][1]);
      pw[1] = cvtpk(s[0][nj][2], s[0][nj][3]);
      *(uint32x2*)((char*)Pl[w] + ((lm * 128 + nj * 32 + lk * 8) ^ swz)) = pw;
    }
    // V fragments via hardware transpose read (shared by both groups)
    uint32x2 tr[2][4][2];
    uint32_t va = vtrb + (uint32_t)(cur * 8192);
    TRRD(tr[0][0][0], "0");    TRRD(tr[0][0][1], "512");
    TRRD(tr[0][1][0], "128");  TRRD(tr[0][1][1], "640");
    TRRD(tr[0][2][0], "256");  TRRD(tr[0][2][1], "768");
    TRRD(tr[0][3][0], "384");  TRRD(tr[0][3][1], "896");
    TRRD(tr[1][0][0], "4096"); TRRD(tr[1][0][1], "4608");
    TRRD(tr[1][1][0], "4224"); TRRD(tr[1][1][1], "4736");
    TRRD(tr[1][2][0], "4352"); TRRD(tr[1][2][1], "4864");
    TRRD(tr[1][3][0], "4480"); TRRD(tr[1][3][1], "4992");
    asm volatile("s_waitcnt lgkmcnt(0)" ::: "memory");
    __builtin_amdgcn_sched_barrier(0);
    // PV group 0
#pragma unroll
    for (int kk = 0; kk < 2; ++kk) {
      bfx8 pf = *(const bfx8*)((char*)Pl[w] + ((lm * 128 + kk * 64 + lk * 16) ^ swz));
#pragma unroll
      for (int nj = 0; nj < 4; ++nj) {
        union { uint32x2 u2[2]; bfx8 v; } u;
        u.u2[0] = tr[kk][nj][0];
        u.u2[1] = tr[kk][nj][1];
        accO[0][nj] = __builtin_amdgcn_mfma_f32_16x16x32_bf16(pf, u.v, accO[0][nj], 0, 0, 0);
      }
    }
    // group 1: P -> LDS (same buffer; in-order DS + compiler alias analysis keep it safe)
#pragma unroll
    for (int nj = 0; nj < 4; ++nj) {
      uint32x2 pw;
      pw[0] = cvtpk(s[1][nj][0], s[1][nj][1]);
      pw[1] = cvtpk(s[1][nj][2], s[1][nj][3]);
      *(uint32x2*)((char*)Pl[w] + ((lm * 128 + nj * 32 + lk * 8) ^ swz)) = pw;
    }
    // PV group 1 (vf regs reused)
#pragma unroll
    for (int kk = 0; kk < 2; ++kk) {
      bfx8 pf = *(const bfx8*)((char*)Pl[w] + ((lm * 128 + kk * 64 + lk * 16) ^ swz));
#pragma unroll
      for (int nj = 0; nj < 4; ++nj) {
        union { uint32x2 u2[2]; bfx8 v; } u;
        u.u2[0] = tr[kk][nj][0];
        u.u2[1] = tr[kk][nj][1];
        accO[1][nj] = __builtin_amdgcn_mfma_f32_16x16x32_bf16(pf, u.v, accO[1][nj], 0, 0, 0);
      }
    }
    __syncthreads();
    cur ^= 1;
  }

  // epilogue: reduce l across the 4 lanes sharing each q, write ctx (B,S,D) bf16
  const int b = bh >> 4, h = bh & 15;
#pragma unroll
  for (int g = 0; g < 2; ++g) {
    float lt = l_part[g];
    lt += __shfl_xor(lt, 16);
    lt += __shfl_xor(lt, 32);
#pragma unroll
    for (int r = 0; r < 4; ++r) {
      float li = __shfl(lt, (l & 48) | (lk * 4 + r));
      float inv = 1.0f / li;
      int q = qt * 128 + g * 64 + w * 16 + lk * 4 + r;
#pragma unroll
      for (int nj = 0; nj < 4; ++nj)
        ctx[((size_t)b * 2048 + q) * 1024 + h * 64 + nj * 16 + lm] = f2b(accO[g][nj][r] * inv);
    }
  }
}

// ---------- launch ----------
extern "C" void kernel_launch(void* const* d_in, const int* in_sizes, int n_in,
                              void* d_out, int out_size, void* d_ws, size_t ws_size,
                              hipStream_t stream) {
  (void)in_sizes; (void)n_in; (void)out_size; (void)ws_size;
  const float* x      = (const float*)d_in[0];
  const float* Wq     = (const float*)d_in[1];
  const float* Wk     = (const float*)d_in[2];
  const float* Wv     = (const float*)d_in[3];
  const float* in_w   = (const float*)d_in[4];
  const float* in_b   = (const float*)d_in[5];
  const float* out_w  = (const float*)d_in[6];
  const float* out_b  = (const float*)d_in[7];
  const float* proj_w = (const float*)d_in[8];
  const float* proj_b = (const float*)d_in[9];
  float* out = (float*)d_out;

  char* ws = (char*)d_ws;
  const size_t MB = 1ull << 20;
  // lifetime-overlapped layout (72 MB + 4 KB total):
  u16* xb   = (u16*)(ws);                    // 16MB; dead after QKV GEMM -> reused as ctx
  u16* ctx  = xb;
  u16* Qh   = (u16*)(ws + 16 * MB);          // 16MB
  u16* Kh   = (u16*)(ws + 32 * MB);          // 16MB; first 6MB doubles as in_w bf16 (prep only)
  u16* Vh   = (u16*)(ws + 48 * MB);          // 16MB; first 8MB = tmpT, +2MB = proj_w bf16 (prep only)
  u16* inwb = Kh;
  u16* tmpT = Vh;
  u16* pwb  = (u16*)(ws + 48 * MB + 8 * MB);
  u16* Wc   = (u16*)(ws + 64 * MB);          // 6MB combined QKV weights
  u16* W2   = (u16*)(ws + 70 * MB);          // 2MB combined output weights
  float* b2 = (float*)(ws + 72 * MB);        // 4KB combined output bias

  f32_to_bf16_k<<<4096, 256, 0, stream>>>(x, xb, 8388608);
  f32_to_bf16_k<<<1536, 256, 0, stream>>>(in_w, inwb, 3145728);
  f32_to_bf16_k<<<512, 256, 0, stream>>>(proj_w, pwb, 1048576);

  TransArgs ta;
  ta.in[0] = Wq; ta.in[1] = Wk; ta.in[2] = Wv; ta.in[3] = out_w;
  for (int z = 0; z < 4; ++z) ta.out[z] = tmpT + (size_t)z * 1048576;
  transpose4_k<<<dim3(16, 16, 4), 256, 0, stream>>>(ta);

  CombArgs ca;
  ca.A[0] = inwb; ca.A[1] = inwb + 1048576; ca.A[2] = inwb + 2097152; ca.A[3] = pwb;
  for (int z = 0; z < 4; ++z) ca.Bt[z] = tmpT + (size_t)z * 1048576;
  ca.C[0] = Wc; ca.C[1] = Wc + 1048576; ca.C[2] = Wc + 2097152; ca.C[3] = W2;
  gemm_combine_k<<<dim3(8, 8, 4), 256, 0, stream>>>(ca);

  make_b2_k<<<1024, 256, 0, stream>>>(proj_w, out_b, proj_b, b2);

  gemm_qkv_k<<<dim3(64, 24), 256, 0, stream>>>(xb, Wc, in_b, Qh, Kh, Vh);
  attn_k<<<dim3(16, 64), 256, 0, stream>>>(Qh, Kh, Vh, ctx);
  gemm_final_k<<<dim3(64, 8), 256, 0, stream>>>(ctx, W2, b2, x, out);
}

// Round 4
// 294.261 us; speedup vs baseline: 1.4272x; 1.0171x over previous
//
#include <hip/hip_runtime.h>
#include <stdint.h>

typedef unsigned short u16;
typedef __attribute__((ext_vector_type(8))) short bfx8;   // 8 bf16 = 4 VGPR (MFMA A/B frag)
typedef __attribute__((ext_vector_type(4))) float fx4;    // MFMA C/D frag
typedef __attribute__((ext_vector_type(2))) unsigned int uint32x2;

// ---------- helpers ----------
static __device__ __forceinline__ u16 f2b(float f) {
  union { float f; uint32_t u; } v; v.f = f;
  uint32_t r = v.u + 0x7fffu + ((v.u >> 16) & 1u);   // RNE
  return (u16)(r >> 16);
}

static __device__ __forceinline__ uint32_t cvtpk(float lo, float hi) {
  uint32_t r;
  asm("v_cvt_pk_bf16_f32 %0, %1, %2" : "=v"(r) : "v"(lo), "v"(hi));
  return r;
}

static __device__ __forceinline__ float ex2(float x) {   // raw v_exp_f32 (2^x)
  float r;
  asm("v_exp_f32 %0, %1" : "=v"(r) : "v"(x));
  return r;
}

static __device__ __forceinline__ void gload16(const void* g, void* lds) {
  __builtin_amdgcn_global_load_lds((const __attribute__((address_space(1))) uint32_t*)g,
                                   (__attribute__((address_space(3))) uint32_t*)lds,
                                   16, 0, 0);
}

// ---------- f32 -> bf16 convert (8 elems/thread, vectorized) ----------
__global__ __launch_bounds__(256) void f32_to_bf16_k(const float* __restrict__ in,
                                                     u16* __restrict__ out, int n) {
  int i = (blockIdx.x * 256 + threadIdx.x) * 8;
  if (i >= n) return;
  float4 a = *(const float4*)(in + i);
  float4 b = *(const float4*)(in + i + 4);
  bfx8 o;
  o[0]=(short)f2b(a.x); o[1]=(short)f2b(a.y); o[2]=(short)f2b(a.z); o[3]=(short)f2b(a.w);
  o[4]=(short)f2b(b.x); o[5]=(short)f2b(b.y); o[6]=(short)f2b(b.z); o[7]=(short)f2b(b.w);
  *(bfx8*)(out + i) = o;
}

// ---------- 1024x1024 f32 transpose -> bf16 (4 matrices batched in z) ----------
struct TransArgs { const float* in[4]; u16* out[4]; };
__global__ __launch_bounds__(256) void transpose4_k(TransArgs ta) {
  const float* in = ta.in[blockIdx.z];
  u16* out = ta.out[blockIdx.z];
  __shared__ u16 t[64][65];
  const int bx = blockIdx.x * 64, by = blockIdx.y * 64;
  const int tid = threadIdx.x;
#pragma unroll
  for (int i = 0; i < 16; ++i) {
    int idx = tid + i * 256; int r = idx >> 6, c = idx & 63;
    t[c][r] = f2b(in[(size_t)(by + r) * 1024 + bx + c]);
  }
  __syncthreads();
#pragma unroll
  for (int i = 0; i < 16; ++i) {
    int idx = tid + i * 256; int r = idx >> 6, c = idx & 63;
    out[(size_t)(bx + r) * 1024 + by + c] = t[r][c];
  }
}

// ---------- b2[f] = proj_b[f] + sum_e proj_w[f][e]*out_b[e] ----------
__global__ __launch_bounds__(256) void make_b2_k(const float* __restrict__ pw,
                                                 const float* __restrict__ ob,
                                                 const float* __restrict__ pb,
                                                 float* __restrict__ b2) {
  const int f = blockIdx.x, tid = threadIdx.x;
  float s = 0.f;
  for (int e = tid; e < 1024; e += 256) s += pw[(size_t)f * 1024 + e] * ob[e];
#pragma unroll
  for (int d = 1; d < 64; d <<= 1) s += __shfl_xor(s, d);
  __shared__ float red[4];
  if ((tid & 63) == 0) red[tid >> 6] = s;
  __syncthreads();
  if (tid == 0) b2[f] = red[0] + red[1] + red[2] + red[3] + pb[f];
}

// ---------- GEMM core: C = A(MxK) * Bt(NxK)^T, 128x128 tile, BK=64, 4 waves ----------
static __device__ __forceinline__ void gemm_core(const u16* __restrict__ A,
                                                 const u16* __restrict__ Bt,
                                                 int K, int bm, int bn,
                                                 u16* As, u16* Bs, fx4 (&acc)[4][4]) {
  const int tid = threadIdx.x, w = tid >> 6, l = tid & 63, lm = l & 15, lk = l >> 4;
  const int wm = w >> 1, wn = w & 1;
  const int nkt = K >> 6;
  for (int kt = 0; kt < nkt; ++kt) {
#pragma unroll
    for (int i = 0; i < 4; ++i) {
      int off = i * 4096 + w * 1024;         // wave-uniform LDS byte base
      int loff = off + l * 16;               // this lane's byte
      int row = loff >> 7, cb = loff & 127;  // tile row, byte-in-row (BK*2=128B rows)
      gload16((const char*)A + ((size_t)(bm * 128 + row) * K + kt * 64) * 2 + cb,
              (char*)As + off);
      gload16((const char*)Bt + ((size_t)(bn * 128 + row) * K + kt * 64) * 2 + cb,
              (char*)Bs + off);
    }
    __syncthreads();
#pragma unroll
    for (int kk = 0; kk < 2; ++kk) {
      bfx8 a[4], b[4];
#pragma unroll
      for (int mi = 0; mi < 4; ++mi)
        a[mi] = *(const bfx8*)((const char*)As + (wm * 64 + mi * 16 + lm) * 128 + lk * 16 + kk * 64);
#pragma unroll
      for (int nj = 0; nj < 4; ++nj)
        b[nj] = *(const bfx8*)((const char*)Bs + (wn * 64 + nj * 16 + lm) * 128 + lk * 16 + kk * 64);
#pragma unroll
      for (int mi = 0; mi < 4; ++mi)
#pragma unroll
        for (int nj = 0; nj < 4; ++nj)
          acc[mi][nj] = __builtin_amdgcn_mfma_f32_16x16x32_bf16(a[mi], b[nj], acc[mi][nj], 0, 0, 0);
    }
    __syncthreads();
  }
}

// ---------- combine GEMMs (4 batched in z): C[f][d] = sum_e A[f][e]*Bt[d][e], bf16 out ----------
struct CombArgs { const u16* A[4]; const u16* Bt[4]; u16* C[4]; };
__global__ __launch_bounds__(256) void gemm_combine_k(CombArgs ca) {
  const int z = blockIdx.z;
  __shared__ u16 As[8192], Bs[8192];
  fx4 acc[4][4];
#pragma unroll
  for (int mi = 0; mi < 4; ++mi)
#pragma unroll
    for (int nj = 0; nj < 4; ++nj) acc[mi][nj] = 0.f;
  gemm_core(ca.A[z], ca.Bt[z], 1024, blockIdx.x, blockIdx.y, As, Bs, acc);
  const int tid = threadIdx.x, w = tid >> 6, l = tid & 63, lm = l & 15, lk = l >> 4;
  const int wm = w >> 1, wn = w & 1;
  u16* C = ca.C[z];
#pragma unroll
  for (int mi = 0; mi < 4; ++mi)
#pragma unroll
    for (int nj = 0; nj < 4; ++nj)
#pragma unroll
      for (int r = 0; r < 4; ++r) {
        int m = blockIdx.x * 128 + wm * 64 + mi * 16 + lk * 4 + r;
        int n = blockIdx.y * 128 + wn * 64 + nj * 16 + lm;
        C[(size_t)m * 1024 + n] = f2b(acc[mi][nj][r]);
      }
}

// ---------- QKV GEMM: [8192x1024]x[3072x1024]^T + in_b ----------
// Q -> (B,H,S,64) plain; K -> same but hd XOR-swizzled (attn LDS swizzle baked in);
// V -> per-(bh,ktile) [k/4][d/16][4][16] subtile-permuted (for ds_read_b64_tr_b16).
__global__ __launch_bounds__(256) void gemm_qkv_k(const u16* __restrict__ xb,
                                                  const u16* __restrict__ Wc,
                                                  const float* __restrict__ bias,
                                                  u16* __restrict__ Qh, u16* __restrict__ Kh,
                                                  u16* __restrict__ Vh) {
  __shared__ u16 As[8192], Bs[8192];
  fx4 acc[4][4];
#pragma unroll
  for (int mi = 0; mi < 4; ++mi)
#pragma unroll
    for (int nj = 0; nj < 4; ++nj) acc[mi][nj] = 0.f;
  gemm_core(xb, Wc, 1024, blockIdx.x, blockIdx.y, As, Bs, acc);
  const int tid = threadIdx.x, w = tid >> 6, l = tid & 63, lm = l & 15, lk = l >> 4;
  const int wm = w >> 1, wn = w & 1;
  const int t = (blockIdx.y * 128) >> 10;                    // tensor select (tile-uniform)
  u16* dst = (t == 0) ? Qh : ((t == 1) ? Kh : Vh);
#pragma unroll
  for (int mi = 0; mi < 4; ++mi)
#pragma unroll
    for (int nj = 0; nj < 4; ++nj)
#pragma unroll
      for (int r = 0; r < 4; ++r) {
        int m = blockIdx.x * 128 + wm * 64 + mi * 16 + lk * 4 + r;
        int n = blockIdx.y * 128 + wn * 64 + nj * 16 + lm;
        float v = acc[mi][nj][r] + bias[n];
        int f = n & 1023, h = f >> 6, hd = f & 63, b = m >> 11, s = m & 2047;
        size_t hb = ((size_t)(b * 16 + h)) * 131072;   // 2048*64
        size_t idx;
        if (t == 2) {
          int sl = s & 63, st = s >> 6;
          idx = hb + (size_t)st * 4096 +
                (size_t)((sl >> 2) * 256 + (hd >> 4) * 64 + (sl & 3) * 16 + (hd & 15));
        } else if (t == 1) {
          idx = hb + (size_t)s * 64 + (hd ^ ((s & 7) << 3));
        } else {
          idx = hb + (size_t)s * 64 + hd;
        }
        dst[idx] = f2b(v);
      }
}

// ---------- final GEMM: ctx[8192x1024] x W2[1024x1024]^T + b2 + x, f32 out ----------
__global__ __launch_bounds__(256) void gemm_final_k(const u16* __restrict__ ctx,
                                                    const u16* __restrict__ W2,
                                                    const float* __restrict__ b2,
                                                    const float* __restrict__ x,
                                                    float* __restrict__ out) {
  __shared__ u16 As[8192], Bs[8192];
  fx4 acc[4][4];
#pragma unroll
  for (int mi = 0; mi < 4; ++mi)
#pragma unroll
    for (int nj = 0; nj < 4; ++nj) acc[mi][nj] = 0.f;
  gemm_core(ctx, W2, 1024, blockIdx.x, blockIdx.y, As, Bs, acc);
  const int tid = threadIdx.x, w = tid >> 6, l = tid & 63, lm = l & 15, lk = l >> 4;
  const int wm = w >> 1, wn = w & 1;
#pragma unroll
  for (int mi = 0; mi < 4; ++mi)
#pragma unroll
    for (int nj = 0; nj < 4; ++nj)
#pragma unroll
      for (int r = 0; r < 4; ++r) {
        int m = blockIdx.x * 128 + wm * 64 + mi * 16 + lk * 4 + r;
        int n = blockIdx.y * 128 + wn * 64 + nj * 16 + lm;
        size_t idx = (size_t)m * 1024 + n;
        out[idx] = acc[mi][nj][r] + b2[n] + x[idx];
      }
}

// ---------- fused attention ----------
// scores = QK^T/8 + tril(1.0), softmax over FULL row (log2 domain), ctx = P*V.
// QBLK=128, 4 waves, 2 q-groups/wave. Triple-buffered K/V staging with
// prefetch-distance-2 + counted vmcnt(4) + RAW s_barrier (one barrier/iter,
// never drains the in-flight prefetch). XCD-chunked block swizzle makes each
// XCD's K/V working set (~2MB) L2-resident.
#define TRRD(d, IMM) asm volatile("ds_read_b64_tr_b16 %0, %1 offset:" IMM : "=v"(d) : "v"(va))

__global__ __launch_bounds__(256) void attn_k(const u16* __restrict__ Qh,
                                              const u16* __restrict__ Kh,
                                              const u16* __restrict__ Vh,
                                              u16* __restrict__ ctx) {
  // XCD-chunked swizzle: consecutive dispatch ids round-robin XCDs; give each
  // XCD a contiguous 128-block chunk (8 bh) so its K/V stream stays in L2.
  const int bl = blockIdx.x;
  const int wk = (bl & 7) * 128 + (bl >> 3);
  const int bh = wk >> 4, qt = wk & 15;
  const int tid = threadIdx.x, w = tid >> 6, l = tid & 63, lm = l & 15, lk = l >> 4;
  __shared__ __align__(16) u16 Ks[3][4096];
  __shared__ __align__(16) u16 Vs[3][4096];
  __shared__ __align__(16) u16 Pl[4][1024];

  const float SC = 0.18033688011112042f;    // 0.125 * log2(e)
  const float MA = 1.4426950408889634f;     // 1.0  * log2(e)
  const float THR = 11.541560327111708f;    // 8.0  * log2(e)

  const size_t base = (size_t)bh * 131072;
  bfx8 qf[2][2];
#pragma unroll
  for (int g = 0; g < 2; ++g) {
    const u16* qp = Qh + base + (size_t)(qt * 128 + g * 64 + w * 16 + lm) * 64;
    qf[g][0] = *(const bfx8*)(qp + lk * 8);
    qf[g][1] = *(const bfx8*)(qp + lk * 8 + 32);
  }
  float m_run[2] = {-INFINITY, -INFINITY};
  float l_part[2] = {0.f, 0.f};
  fx4 accO[2][4];
#pragma unroll
  for (int g = 0; g < 2; ++g)
#pragma unroll
    for (int nj = 0; nj < 4; ++nj) accO[g][nj] = 0.f;

  const char* Kg = (const char*)(Kh + base);
  const char* Vg = (const char*)(Vh + base);
  const int o0 = w * 1024 + l * 16, o1 = o0 + 4096;

  const int swz = (lm & 7) << 4;
  const uint32_t vs_base =
      (uint32_t)(uintptr_t)(__attribute__((address_space(3))) char*)&Vs[0][0];
  const uint32_t vtrb = vs_base + (uint32_t)(lk * 1024 + lm * 8);

#define STAGE(t, s)                                        \
  {                                                        \
    const char* kg_ = Kg + (t) * 8192;                     \
    const char* vg_ = Vg + (t) * 8192;                     \
    gload16(kg_ + o0, (char*)Ks[s] + o0);                  \
    gload16(kg_ + o1, (char*)Ks[s] + o1);                  \
    gload16(vg_ + o0, (char*)Vs[s] + o0);                  \
    gload16(vg_ + o1, (char*)Vs[s] + o1);                  \
  }

  // prologue: tiles 0,1 in flight; wait for tile 0 only (tile 1 stays in flight)
  STAGE(0, 0);
  STAGE(1, 1);
  asm volatile("s_waitcnt vmcnt(4)" ::: "memory");
  __builtin_amdgcn_s_barrier();
  __builtin_amdgcn_sched_barrier(0);

  int s0 = 0, s1 = 1, s2 = 2;
  for (int kt = 0; kt < 32; ++kt) {
    if (kt + 2 < 32) STAGE(kt + 2, s2);   // prefetch distance 2 into the slot freed at iter kt-1
    __builtin_amdgcn_sched_barrier(0);

    const char* Kc = (const char*)Ks[s0];
    // QK^T (swapped): per group, lane holds keys nj*16+lk*4+r for q = lm
    fx4 s[2][4];
#pragma unroll
    for (int g = 0; g < 2; ++g)
#pragma unroll
      for (int nj = 0; nj < 4; ++nj) s[g][nj] = 0.f;
    __builtin_amdgcn_s_setprio(1);
#pragma unroll
    for (int kk = 0; kk < 2; ++kk) {
      bfx8 kf[4];
#pragma unroll
      for (int nj = 0; nj < 4; ++nj)
        kf[nj] = *(const bfx8*)(Kc + nj * 2048 + lm * 128 +
                                (((kk * 4 + lk) ^ (lm & 7)) << 4));
#pragma unroll
      for (int g = 0; g < 2; ++g)
#pragma unroll
        for (int nj = 0; nj < 4; ++nj)
          s[g][nj] = __builtin_amdgcn_mfma_f32_16x16x32_bf16(kf[nj], qf[g][kk], s[g][nj], 0, 0, 0);
    }
    __builtin_amdgcn_s_setprio(0);
    // scale to log2 domain + additive tril mask (tile-uniform except diagonal tile)
#pragma unroll
    for (int g = 0; g < 2; ++g) {
      const int dk = kt - 2 * qt - g;
      if (dk < 0) {
#pragma unroll
        for (int nj = 0; nj < 4; ++nj)
#pragma unroll
          for (int r = 0; r < 4; ++r) s[g][nj][r] = fmaf(s[g][nj][r], SC, MA);
      } else if (dk > 0) {
#pragma unroll
        for (int nj = 0; nj < 4; ++nj)
#pragma unroll
          for (int r = 0; r < 4; ++r) s[g][nj][r] *= SC;
      } else {
        const int qg = qt * 128 + g * 64 + w * 16 + lm;
#pragma unroll
        for (int nj = 0; nj < 4; ++nj)
#pragma unroll
          for (int r = 0; r < 4; ++r) {
            int key = kt * 64 + nj * 16 + lk * 4 + r;
            s[g][nj][r] = s[g][nj][r] * SC + ((key <= qg) ? MA : 0.0f);
          }
      }
      // online softmax in log2 domain, defer-max
      float mx = fmaxf(fmaxf(fmaxf(s[g][0][0], s[g][0][1]), fmaxf(s[g][0][2], s[g][0][3])),
                       fmaxf(fmaxf(s[g][1][0], s[g][1][1]), fmaxf(s[g][1][2], s[g][1][3])));
      mx = fmaxf(mx, fmaxf(fmaxf(fmaxf(s[g][2][0], s[g][2][1]), fmaxf(s[g][2][2], s[g][2][3])),
                           fmaxf(fmaxf(s[g][3][0], s[g][3][1]), fmaxf(s[g][3][2], s[g][3][3]))));
      if (!__all(mx <= m_run[g] + THR)) {
        mx = fmaxf(mx, __shfl_xor(mx, 16));
        mx = fmaxf(mx, __shfl_xor(mx, 32));
        float mn = fmaxf(m_run[g], mx);
        float corr = ex2(m_run[g] - mn);
        m_run[g] = mn;
        l_part[g] *= corr;
#pragma unroll
        for (int r = 0; r < 4; ++r) {
          float cr = __shfl(corr, (l & 48) | (lk * 4 + r));
#pragma unroll
          for (int nj = 0; nj < 4; ++nj) accO[g][nj][r] *= cr;
        }
      }
      float lsum = 0.f;
#pragma unroll
      for (int nj = 0; nj < 4; ++nj)
#pragma unroll
        for (int r = 0; r < 4; ++r) {
          float p = ex2(s[g][nj][r] - m_run[g]);
          s[g][nj][r] = p;
          lsum += p;
        }
      l_part[g] += lsum;
    }
    // group 0: P -> LDS (cvt_pk pairs, 4x ds_write_b64)
#pragma unroll
    for (int nj = 0; nj < 4; ++nj) {
      uint32x2 pw;
      pw[0] = cvtpk(s[0][nj][0], s[0][nj][1]);
      pw[1] = cvtpk(s[0][nj][2], s[0][nj][3]);
      *(uint32x2*)((char*)Pl[w] + ((lm * 128 + nj * 32 + lk * 8) ^ swz)) = pw;
    }
    // V fragments via hardware transpose read (shared by both groups)
    uint32x2 tr[2][4][2];
    uint32_t va = vtrb + (uint32_t)(s0 * 8192);
    TRRD(tr[0][0][0], "0");    TRRD(tr[0][0][1], "512");
    TRRD(tr[0][1][0], "128");  TRRD(tr[0][1][1], "640");
    TRRD(tr[0][2][0], "256");  TRRD(tr[0][2][1], "768");
    TRRD(tr[0][3][0], "384");  TRRD(tr[0][3][1], "896");
    TRRD(tr[1][0][0], "4096"); TRRD(tr[1][0][1], "4608");
    TRRD(tr[1][1][0], "4224"); TRRD(tr[1][1][1], "4736");
    TRRD(tr[1][2][0], "4352"); TRRD(tr[1][2][1], "4864");
    TRRD(tr[1][3][0], "4480"); TRRD(tr[1][3][1], "4992");
    asm volatile("s_waitcnt lgkmcnt(0)" ::: "memory");
    __builtin_amdgcn_sched_barrier(0);
    // PV group 0
    __builtin_amdgcn_s_setprio(1);
#pragma unroll
    for (int kk = 0; kk < 2; ++kk) {
      bfx8 pf = *(const bfx8*)((char*)Pl[w] + ((lm * 128 + kk * 64 + lk * 16) ^ swz));
#pragma unroll
      for (int nj = 0; nj < 4; ++nj) {
        union { uint32x2 u2[2]; bfx8 v; } u;
        u.u2[0] = tr[kk][nj][0];
        u.u2[1] = tr[kk][nj][1];
        accO[0][nj] = __builtin_amdgcn_mfma_f32_16x16x32_bf16(pf, u.v, accO[0][nj], 0, 0, 0);
      }
    }
    __builtin_amdgcn_s_setprio(0);
    // group 1: P -> LDS (same buffer; per-wave in-order DS keeps it safe)
#pragma unroll
    for (int nj = 0; nj < 4; ++nj) {
      uint32x2 pw;
      pw[0] = cvtpk(s[1][nj][0], s[1][nj][1]);
      pw[1] = cvtpk(s[1][nj][2], s[1][nj][3]);
      *(uint32x2*)((char*)Pl[w] + ((lm * 128 + nj * 32 + lk * 8) ^ swz)) = pw;
    }
    __builtin_amdgcn_s_setprio(1);
#pragma unroll
    for (int kk = 0; kk < 2; ++kk) {
      bfx8 pf = *(const bfx8*)((char*)Pl[w] + ((lm * 128 + kk * 64 + lk * 16) ^ swz));
#pragma unroll
      for (int nj = 0; nj < 4; ++nj) {
        union { uint32x2 u2[2]; bfx8 v; } u;
        u.u2[0] = tr[kk][nj][0];
        u.u2[1] = tr[kk][nj][1];
        accO[1][nj] = __builtin_amdgcn_mfma_f32_16x16x32_bf16(pf, u.v, accO[1][nj], 0, 0, 0);
      }
    }
    __builtin_amdgcn_s_setprio(0);

    if (kt < 31) {
      // retire tile kt+1 (keep tile kt+2's 4 loads in flight); tail drains fully
      if (kt < 30) asm volatile("s_waitcnt vmcnt(4)" ::: "memory");
      else         asm volatile("s_waitcnt vmcnt(0)" ::: "memory");
      __builtin_amdgcn_s_barrier();
      __builtin_amdgcn_sched_barrier(0);
    }
    int tswp = s0; s0 = s1; s1 = s2; s2 = tswp;
  }
#undef STAGE

  // epilogue: reduce l across the 4 lanes sharing each q, write ctx (B,S,D) bf16
  const int b = bh >> 4, h = bh & 15;
#pragma unroll
  for (int g = 0; g < 2; ++g) {
    float lt = l_part[g];
    lt += __shfl_xor(lt, 16);
    lt += __shfl_xor(lt, 32);
#pragma unroll
    for (int r = 0; r < 4; ++r) {
      float li = __shfl(lt, (l & 48) | (lk * 4 + r));
      float inv = 1.0f / li;
      int q = qt * 128 + g * 64 + w * 16 + lk * 4 + r;
#pragma unroll
      for (int nj = 0; nj < 4; ++nj)
        ctx[((size_t)b * 2048 + q) * 1024 + h * 64 + nj * 16 + lm] = f2b(accO[g][nj][r] * inv);
    }
  }
}

// ---------- launch ----------
extern "C" void kernel_launch(void* const* d_in, const int* in_sizes, int n_in,
                              void* d_out, int out_size, void* d_ws, size_t ws_size,
                              hipStream_t stream) {
  (void)in_sizes; (void)n_in; (void)out_size; (void)ws_size;
  const float* x      = (const float*)d_in[0];
  const float* Wq     = (const float*)d_in[1];
  const float* Wk     = (const float*)d_in[2];
  const float* Wv     = (const float*)d_in[3];
  const float* in_w   = (const float*)d_in[4];
  const float* in_b   = (const float*)d_in[5];
  const float* out_w  = (const float*)d_in[6];
  const float* out_b  = (const float*)d_in[7];
  const float* proj_w = (const float*)d_in[8];
  const float* proj_b = (const float*)d_in[9];
  float* out = (float*)d_out;

  char* ws = (char*)d_ws;
  const size_t MB = 1ull << 20;
  // lifetime-overlapped layout (72 MB + 4 KB total):
  u16* xb   = (u16*)(ws);                    // 16MB; dead after QKV GEMM -> reused as ctx
  u16* ctx  = xb;
  u16* Qh   = (u16*)(ws + 16 * MB);          // 16MB
  u16* Kh   = (u16*)(ws + 32 * MB);          // 16MB; first 6MB doubles as in_w bf16 (prep only)
  u16* Vh   = (u16*)(ws + 48 * MB);          // 16MB; first 8MB = tmpT, +2MB = proj_w bf16 (prep only)
  u16* inwb = Kh;
  u16* tmpT = Vh;
  u16* pwb  = (u16*)(ws + 48 * MB + 8 * MB);
  u16* Wc   = (u16*)(ws + 64 * MB);          // 6MB combined QKV weights
  u16* W2   = (u16*)(ws + 70 * MB);          // 2MB combined output weights
  float* b2 = (float*)(ws + 72 * MB);        // 4KB combined output bias

  f32_to_bf16_k<<<4096, 256, 0, stream>>>(x, xb, 8388608);
  f32_to_bf16_k<<<1536, 256, 0, stream>>>(in_w, inwb, 3145728);
  f32_to_bf16_k<<<512, 256, 0, stream>>>(proj_w, pwb, 1048576);

  TransArgs ta;
  ta.in[0] = Wq; ta.in[1] = Wk; ta.in[2] = Wv; ta.in[3] = out_w;
  for (int z = 0; z < 4; ++z) ta.out[z] = tmpT + (size_t)z * 1048576;
  transpose4_k<<<dim3(16, 16, 4), 256, 0, stream>>>(ta);

  CombArgs ca;
  ca.A[0] = inwb; ca.A[1] = inwb + 1048576; ca.A[2] = inwb + 2097152; ca.A[3] = pwb;
  for (int z = 0; z < 4; ++z) ca.Bt[z] = tmpT + (size_t)z * 1048576;
  ca.C[0] = Wc; ca.C[1] = Wc + 1048576; ca.C[2] = Wc + 2097152; ca.C[3] = W2;
  gemm_combine_k<<<dim3(8, 8, 4), 256, 0, stream>>>(ca);

  make_b2_k<<<1024, 256, 0, stream>>>(proj_w, out_b, proj_b, b2);

  gemm_qkv_k<<<dim3(64, 24), 256, 0, stream>>>(xb, Wc, in_b, Qh, Kh, Vh);
  attn_k<<<1024, 256, 0, stream>>>(Qh, Kh, Vh, ctx);
  gemm_final_k<<<dim3(64, 8), 256, 0, stream>>>(ctx, W2, b2, x, out);
}

// Round 5
// 286.346 us; speedup vs baseline: 1.4667x; 1.0276x over previous
//
#include <hip/hip_runtime.h>
#include <stdint.h>

typedef unsigned short u16;
typedef __attribute__((ext_vector_type(8))) short bfx8;   // 8 bf16 = 4 VGPR (MFMA A/B frag)
typedef __attribute__((ext_vector_type(4))) float fx4;    // MFMA C/D frag
typedef __attribute__((ext_vector_type(2))) unsigned int uint32x2;

// ---------- helpers ----------
static __device__ __forceinline__ u16 f2b(float f) {
  union { float f; uint32_t u; } v; v.f = f;
  uint32_t r = v.u + 0x7fffu + ((v.u >> 16) & 1u);   // RNE
  return (u16)(r >> 16);
}

static __device__ __forceinline__ uint32_t cvtpk(float lo, float hi) {
  uint32_t r;
  asm("v_cvt_pk_bf16_f32 %0, %1, %2" : "=v"(r) : "v"(lo), "v"(hi));
  return r;
}

static __device__ __forceinline__ float ex2(float x) {   // raw v_exp_f32 (2^x)
  float r;
  asm("v_exp_f32 %0, %1" : "=v"(r) : "v"(x));
  return r;
}

static __device__ __forceinline__ void gload16(const void* g, void* lds) {
  __builtin_amdgcn_global_load_lds((const __attribute__((address_space(1))) uint32_t*)g,
                                   (__attribute__((address_space(3))) uint32_t*)lds,
                                   16, 0, 0);
}

// ---------- f32 -> bf16 convert (8 elems/thread, vectorized) ----------
__global__ __launch_bounds__(256) void f32_to_bf16_k(const float* __restrict__ in,
                                                     u16* __restrict__ out, int n) {
  int i = (blockIdx.x * 256 + threadIdx.x) * 8;
  if (i >= n) return;
  float4 a = *(const float4*)(in + i);
  float4 b = *(const float4*)(in + i + 4);
  bfx8 o;
  o[0]=(short)f2b(a.x); o[1]=(short)f2b(a.y); o[2]=(short)f2b(a.z); o[3]=(short)f2b(a.w);
  o[4]=(short)f2b(b.x); o[5]=(short)f2b(b.y); o[6]=(short)f2b(b.z); o[7]=(short)f2b(b.w);
  *(bfx8*)(out + i) = o;
}

// ---------- 1024x1024 f32 transpose -> bf16 (4 matrices batched in z) ----------
struct TransArgs { const float* in[4]; u16* out[4]; };
__global__ __launch_bounds__(256) void transpose4_k(TransArgs ta) {
  const float* in = ta.in[blockIdx.z];
  u16* out = ta.out[blockIdx.z];
  __shared__ u16 t[64][65];
  const int bx = blockIdx.x * 64, by = blockIdx.y * 64;
  const int tid = threadIdx.x;
#pragma unroll
  for (int i = 0; i < 16; ++i) {
    int idx = tid + i * 256; int r = idx >> 6, c = idx & 63;
    t[c][r] = f2b(in[(size_t)(by + r) * 1024 + bx + c]);
  }
  __syncthreads();
#pragma unroll
  for (int i = 0; i < 16; ++i) {
    int idx = tid + i * 256; int r = idx >> 6, c = idx & 63;
    out[(size_t)(bx + r) * 1024 + by + c] = t[r][c];
  }
}

// ---------- b2[f] = proj_b[f] + sum_e proj_w[f][e]*out_b[e] ----------
__global__ __launch_bounds__(256) void make_b2_k(const float* __restrict__ pw,
                                                 const float* __restrict__ ob,
                                                 const float* __restrict__ pb,
                                                 float* __restrict__ b2) {
  const int f = blockIdx.x, tid = threadIdx.x;
  float s = 0.f;
  for (int e = tid; e < 1024; e += 256) s += pw[(size_t)f * 1024 + e] * ob[e];
#pragma unroll
  for (int d = 1; d < 64; d <<= 1) s += __shfl_xor(s, d);
  __shared__ float red[4];
  if ((tid & 63) == 0) red[tid >> 6] = s;
  __syncthreads();
  if (tid == 0) b2[f] = red[0] + red[1] + red[2] + red[3] + pb[f];
}

// ---------- GEMM core: C = A(MxK) * Bt(NxK)^T, 128x128 tile, BK=64, 4 waves ----------
static __device__ __forceinline__ void gemm_core(const u16* __restrict__ A,
                                                 const u16* __restrict__ Bt,
                                                 int K, int bm, int bn,
                                                 u16* As, u16* Bs, fx4 (&acc)[4][4]) {
  const int tid = threadIdx.x, w = tid >> 6, l = tid & 63, lm = l & 15, lk = l >> 4;
  const int wm = w >> 1, wn = w & 1;
  const int nkt = K >> 6;
  for (int kt = 0; kt < nkt; ++kt) {
#pragma unroll
    for (int i = 0; i < 4; ++i) {
      int off = i * 4096 + w * 1024;         // wave-uniform LDS byte base
      int loff = off + l * 16;               // this lane's byte
      int row = loff >> 7, cb = loff & 127;  // tile row, byte-in-row (BK*2=128B rows)
      gload16((const char*)A + ((size_t)(bm * 128 + row) * K + kt * 64) * 2 + cb,
              (char*)As + off);
      gload16((const char*)Bt + ((size_t)(bn * 128 + row) * K + kt * 64) * 2 + cb,
              (char*)Bs + off);
    }
    __syncthreads();
#pragma unroll
    for (int kk = 0; kk < 2; ++kk) {
      bfx8 a[4], b[4];
#pragma unroll
      for (int mi = 0; mi < 4; ++mi)
        a[mi] = *(const bfx8*)((const char*)As + (wm * 64 + mi * 16 + lm) * 128 + lk * 16 + kk * 64);
#pragma unroll
      for (int nj = 0; nj < 4; ++nj)
        b[nj] = *(const bfx8*)((const char*)Bs + (wn * 64 + nj * 16 + lm) * 128 + lk * 16 + kk * 64);
#pragma unroll
      for (int mi = 0; mi < 4; ++mi)
#pragma unroll
        for (int nj = 0; nj < 4; ++nj)
          acc[mi][nj] = __builtin_amdgcn_mfma_f32_16x16x32_bf16(a[mi], b[nj], acc[mi][nj], 0, 0, 0);
    }
    __syncthreads();
  }
}

// ---------- combine GEMMs (4 batched in z): C[f][d] = sum_e A[f][e]*Bt[d][e], bf16 out ----------
struct CombArgs { const u16* A[4]; const u16* Bt[4]; u16* C[4]; };
__global__ __launch_bounds__(256) void gemm_combine_k(CombArgs ca) {
  const int z = blockIdx.z;
  __shared__ u16 As[8192], Bs[8192];
  fx4 acc[4][4];
#pragma unroll
  for (int mi = 0; mi < 4; ++mi)
#pragma unroll
    for (int nj = 0; nj < 4; ++nj) acc[mi][nj] = 0.f;
  gemm_core(ca.A[z], ca.Bt[z], 1024, blockIdx.x, blockIdx.y, As, Bs, acc);
  const int tid = threadIdx.x, w = tid >> 6, l = tid & 63, lm = l & 15, lk = l >> 4;
  const int wm = w >> 1, wn = w & 1;
  u16* C = ca.C[z];
#pragma unroll
  for (int mi = 0; mi < 4; ++mi)
#pragma unroll
    for (int nj = 0; nj < 4; ++nj)
#pragma unroll
      for (int r = 0; r < 4; ++r) {
        int m = blockIdx.x * 128 + wm * 64 + mi * 16 + lk * 4 + r;
        int n = blockIdx.y * 128 + wn * 64 + nj * 16 + lm;
        C[(size_t)m * 1024 + n] = f2b(acc[mi][nj][r]);
      }
}

// ---------- QKV GEMM: [8192x1024]x[3072x1024]^T + in_b ----------
// Q -> (B,H,S,64) plain; K -> (B,H,S,64) with hd XOR-swizzled (attn LDS swizzle baked in);
// V -> per-(bh,ktile) TRANSPOSED tile Vt[64 d][64 k], row-XOR-swizzled (same pattern as K)
//      so attn's PV B-operand is a clean ds_read_b128 (no tr-read).
__global__ __launch_bounds__(256) void gemm_qkv_k(const u16* __restrict__ xb,
                                                  const u16* __restrict__ Wc,
                                                  const float* __restrict__ bias,
                                                  u16* __restrict__ Qh, u16* __restrict__ Kh,
                                                  u16* __restrict__ Vh) {
  __shared__ u16 As[8192], Bs[8192];
  fx4 acc[4][4];
#pragma unroll
  for (int mi = 0; mi < 4; ++mi)
#pragma unroll
    for (int nj = 0; nj < 4; ++nj) acc[mi][nj] = 0.f;
  gemm_core(xb, Wc, 1024, blockIdx.x, blockIdx.y, As, Bs, acc);
  const int tid = threadIdx.x, w = tid >> 6, l = tid & 63, lm = l & 15, lk = l >> 4;
  const int wm = w >> 1, wn = w & 1;
  const int t = (blockIdx.y * 128) >> 10;                    // tensor select (tile-uniform)
  u16* dst = (t == 0) ? Qh : ((t == 1) ? Kh : Vh);
#pragma unroll
  for (int mi = 0; mi < 4; ++mi)
#pragma unroll
    for (int nj = 0; nj < 4; ++nj)
#pragma unroll
      for (int r = 0; r < 4; ++r) {
        int m = blockIdx.x * 128 + wm * 64 + mi * 16 + lk * 4 + r;
        int n = blockIdx.y * 128 + wn * 64 + nj * 16 + lm;
        float v = acc[mi][nj][r] + bias[n];
        int f = n & 1023, h = f >> 6, hd = f & 63, b = m >> 11, s = m & 2047;
        size_t hb = ((size_t)(b * 16 + h)) * 131072;   // 2048*64
        size_t idx;
        if (t == 2) {
          int sl = s & 63, st = s >> 6;                // Vt[d=hd][k=sl], row-swizzled
          idx = hb + (size_t)st * 4096 + (size_t)(hd * 64 + (sl ^ ((hd & 7) << 3)));
        } else if (t == 1) {
          idx = hb + (size_t)s * 64 + (hd ^ ((s & 7) << 3));
        } else {
          idx = hb + (size_t)s * 64 + hd;
        }
        dst[idx] = f2b(v);
      }
}

// ---------- final GEMM: ctx[8192x1024] x W2[1024x1024]^T + b2 + x, f32 out ----------
__global__ __launch_bounds__(256) void gemm_final_k(const u16* __restrict__ ctx,
                                                    const u16* __restrict__ W2,
                                                    const float* __restrict__ b2,
                                                    const float* __restrict__ x,
                                                    float* __restrict__ out) {
  __shared__ u16 As[8192], Bs[8192];
  fx4 acc[4][4];
#pragma unroll
  for (int mi = 0; mi < 4; ++mi)
#pragma unroll
    for (int nj = 0; nj < 4; ++nj) acc[mi][nj] = 0.f;
  gemm_core(ctx, W2, 1024, blockIdx.x, blockIdx.y, As, Bs, acc);
  const int tid = threadIdx.x, w = tid >> 6, l = tid & 63, lm = l & 15, lk = l >> 4;
  const int wm = w >> 1, wn = w & 1;
#pragma unroll
  for (int mi = 0; mi < 4; ++mi)
#pragma unroll
    for (int nj = 0; nj < 4; ++nj)
#pragma unroll
      for (int r = 0; r < 4; ++r) {
        int m = blockIdx.x * 128 + wm * 64 + mi * 16 + lk * 4 + r;
        int n = blockIdx.y * 128 + wn * 64 + nj * 16 + lm;
        size_t idx = (size_t)m * 1024 + n;
        out[idx] = acc[mi][nj][r] + b2[n] + x[idx];
      }
}

// ---------- fused attention ----------
// scores = QK^T/8 + tril(1.0), softmax over FULL row (log2 domain), ctx = P*V.
// 8 waves (512 thr), QBLK=256 (2 groups x 16 q-rows per wave), KV tiles of 64.
// Triple-buffered linear staging (1 gload16/thread/tile each for K and V),
// prefetch-distance-2 + counted vmcnt(2). V stored transposed+swizzled globally
// so PV uses plain ds_read_b128 (no tr-read). Softmax bias-folded: one FMA does
// scale+mask+max-subtract; rescale path incremental.
__global__ __launch_bounds__(512, 4) void attn_k(const u16* __restrict__ Qh,
                                                 const u16* __restrict__ Kh,
                                                 const u16* __restrict__ Vh,
                                                 u16* __restrict__ ctx) {
  // XCD-chunked swizzle: 512 blocks / 8 XCDs = 64 contiguous work items per XCD
  // (8 bh, all 8 q-tiles) -> K/V stream stays L2-resident.
  const int bl = blockIdx.x;
  const int wk = (bl & 7) * 64 + (bl >> 3);
  const int bh = wk >> 3, qt = wk & 7;
  const int tid = threadIdx.x, w = tid >> 6, l = tid & 63, lm = l & 15, lk = l >> 4;
  __shared__ __align__(16) u16 Ks[3][4096];
  __shared__ __align__(16) u16 Vs[3][4096];
  __shared__ __align__(16) u16 Pl[8][1024];

  const float SC = 0.18033688011112042f;    // 0.125 * log2(e)
  const float MA = 1.4426950408889634f;     // 1.0  * log2(e)
  const float THR = 11.541560327111708f;    // 8.0  * log2(e)

  const size_t base = (size_t)bh * 131072;
  const int gb0 = qt * 256 + w * 32;        // this wave's q-row base (group g adds g*16)
  bfx8 qf[2][2];
#pragma unroll
  for (int g = 0; g < 2; ++g) {
    const u16* qp = Qh + base + (size_t)(gb0 + g * 16 + lm) * 64;
    qf[g][0] = *(const bfx8*)(qp + lk * 8);
    qf[g][1] = *(const bfx8*)(qp + lk * 8 + 32);
  }
  float m_run[2] = {-1024.f, -1024.f};      // finite init (incremental rescale needs it)
  float l_part[2] = {0.f, 0.f};
  fx4 accO[2][4];
#pragma unroll
  for (int g = 0; g < 2; ++g)
#pragma unroll
    for (int nj = 0; nj < 4; ++nj) accO[g][nj] = 0.f;

  const char* Kg = (const char*)(Kh + base);
  const char* Vg = (const char*)(Vh + base);
  const int o = tid * 16;                   // 512 thr x 16B = one full 8KB tile
  const int swz = (lm & 7) << 4;

#define STAGE(t, s)                                          \
  {                                                          \
    gload16(Kg + (size_t)(t) * 8192 + o, (char*)Ks[s] + o);  \
    gload16(Vg + (size_t)(t) * 8192 + o, (char*)Vs[s] + o);  \
  }

  // prologue: tiles 0,1 in flight; retire tile 0 only
  STAGE(0, 0);
  STAGE(1, 1);
  asm volatile("s_waitcnt vmcnt(2)" ::: "memory");
  __builtin_amdgcn_s_barrier();
  __builtin_amdgcn_sched_barrier(0);

  int s0 = 0, s1 = 1, s2 = 2;
  for (int kt = 0; kt < 32; ++kt) {
    if (kt + 2 < 32) STAGE(kt + 2, s2);
    __builtin_amdgcn_sched_barrier(0);

    const char* Kc = (const char*)Ks[s0];
    const char* Vc = (const char*)Vs[s0];
    // QK^T (swapped): lane holds keys nj*16+lk*4+r for q = gb0+g*16+lm
    fx4 sg[2][4];
#pragma unroll
    for (int g = 0; g < 2; ++g)
#pragma unroll
      for (int nj = 0; nj < 4; ++nj) sg[g][nj] = 0.f;
    __builtin_amdgcn_s_setprio(1);
#pragma unroll
    for (int kk = 0; kk < 2; ++kk) {
      bfx8 kf[4];
#pragma unroll
      for (int nj = 0; nj < 4; ++nj)
        kf[nj] = *(const bfx8*)(Kc + nj * 2048 + lm * 128 +
                                (((kk * 4 + lk) ^ (lm & 7)) << 4));
#pragma unroll
      for (int g = 0; g < 2; ++g)
#pragma unroll
        for (int nj = 0; nj < 4; ++nj)
          sg[g][nj] = __builtin_amdgcn_mfma_f32_16x16x32_bf16(kf[nj], qf[g][kk], sg[g][nj], 0, 0, 0);
    }
    __builtin_amdgcn_s_setprio(0);

    // softmax per group (log2 domain, bias-folded, incremental defer-max)
#pragma unroll
    for (int g = 0; g < 2; ++g) {
      const int dk = kt - ((gb0 + g * 16) >> 6);
      float cO = -m_run[g], cI = cO + MA;
      if (dk < 0) {
#pragma unroll
        for (int nj = 0; nj < 4; ++nj)
#pragma unroll
          for (int r = 0; r < 4; ++r) sg[g][nj][r] = fmaf(sg[g][nj][r], SC, cI);
      } else if (dk > 0) {
#pragma unroll
        for (int nj = 0; nj < 4; ++nj)
#pragma unroll
          for (int r = 0; r < 4; ++r) sg[g][nj][r] = fmaf(sg[g][nj][r], SC, cO);
      } else {
        const int qg = gb0 + g * 16 + lm;
#pragma unroll
        for (int nj = 0; nj < 4; ++nj)
#pragma unroll
          for (int r = 0; r < 4; ++r) {
            int key = kt * 64 + nj * 16 + lk * 4 + r;
            sg[g][nj][r] = fmaf(sg[g][nj][r], SC, (key <= qg) ? cI : cO);
          }
      }
      float mx = fmaxf(fmaxf(fmaxf(sg[g][0][0], sg[g][0][1]), fmaxf(sg[g][0][2], sg[g][0][3])),
                       fmaxf(fmaxf(sg[g][1][0], sg[g][1][1]), fmaxf(sg[g][1][2], sg[g][1][3])));
      mx = fmaxf(mx, fmaxf(fmaxf(fmaxf(sg[g][2][0], sg[g][2][1]), fmaxf(sg[g][2][2], sg[g][2][3])),
                           fmaxf(fmaxf(sg[g][3][0], sg[g][3][1]), fmaxf(sg[g][3][2], sg[g][3][3]))));
      if (!__all(mx <= THR)) {
        float mxr = fmaxf(mx, __shfl_xor(mx, 16));
        mxr = fmaxf(mxr, __shfl_xor(mxr, 32));
        float d = fmaxf(mxr, 0.f);
        float corr = ex2(-d);
        m_run[g] += d;
        l_part[g] *= corr;
#pragma unroll
        for (int r = 0; r < 4; ++r) {
          float cr = __shfl(corr, (l & 48) | (lk * 4 + r));
#pragma unroll
          for (int nj = 0; nj < 4; ++nj) accO[g][nj][r] *= cr;
        }
#pragma unroll
        for (int nj = 0; nj < 4; ++nj)
#pragma unroll
          for (int r = 0; r < 4; ++r) sg[g][nj][r] -= d;
      }
      float lsum = 0.f;
#pragma unroll
      for (int nj = 0; nj < 4; ++nj)
#pragma unroll
        for (int r = 0; r < 4; ++r) {
          float p = ex2(sg[g][nj][r]);
          sg[g][nj][r] = p;
          lsum += p;
        }
      l_part[g] += lsum;
    }

    // group 0: P -> LDS (cvt_pk pairs, 4x ds_write_b64)
#pragma unroll
    for (int nj = 0; nj < 4; ++nj) {
      uint32x2 pw;
      pw[0] = cvtpk(sg[0][nj][0], sg[0][nj][1]);
      pw[1] = cvtpk(sg[0][nj][2], sg[0][nj][3]);
      *(uint32x2*)((char*)Pl[w] + ((lm * 128 + nj * 32 + lk * 8) ^ swz)) = pw;
    }
    // V fragments: plain swizzled b128 reads from transposed-tile Vt (shared by groups)
    bfx8 vf[2][4];
#pragma unroll
    for (int kk = 0; kk < 2; ++kk)
#pragma unroll
      for (int nj = 0; nj < 4; ++nj)
        vf[kk][nj] = *(const bfx8*)(Vc + nj * 2048 + lm * 128 +
                                    (((kk * 4 + lk) ^ (lm & 7)) << 4));
    // PV group 0
    __builtin_amdgcn_s_setprio(1);
#pragma unroll
    for (int kk = 0; kk < 2; ++kk) {
      bfx8 pf = *(const bfx8*)((char*)Pl[w] + ((lm * 128 + kk * 64 + lk * 16) ^ swz));
#pragma unroll
      for (int nj = 0; nj < 4; ++nj)
        accO[0][nj] = __builtin_amdgcn_mfma_f32_16x16x32_bf16(pf, vf[kk][nj], accO[0][nj], 0, 0, 0);
    }
    __builtin_amdgcn_s_setprio(0);
    // group 1: P -> LDS (same per-wave buffer; same-wave DS ordering + aliasing keep it safe)
#pragma unroll
    for (int nj = 0; nj < 4; ++nj) {
      uint32x2 pw;
      pw[0] = cvtpk(sg[1][nj][0], sg[1][nj][1]);
      pw[1] = cvtpk(sg[1][nj][2], sg[1][nj][3]);
      *(uint32x2*)((char*)Pl[w] + ((lm * 128 + nj * 32 + lk * 8) ^ swz)) = pw;
    }
    __builtin_amdgcn_s_setprio(1);
#pragma unroll
    for (int kk = 0; kk < 2; ++kk) {
      bfx8 pf = *(const bfx8*)((char*)Pl[w] + ((lm * 128 + kk * 64 + lk * 16) ^ swz));
#pragma unroll
      for (int nj = 0; nj < 4; ++nj)
        accO[1][nj] = __builtin_amdgcn_mfma_f32_16x16x32_bf16(pf, vf[kk][nj], accO[1][nj], 0, 0, 0);
    }
    __builtin_amdgcn_s_setprio(0);

    if (kt < 31) {
      // retire tile kt+1; keep tile kt+2's 2 loads in flight (tail drains fully)
      if (kt < 30) asm volatile("s_waitcnt vmcnt(2)" ::: "memory");
      else         asm volatile("s_waitcnt vmcnt(0)" ::: "memory");
      __builtin_amdgcn_s_barrier();
      __builtin_amdgcn_sched_barrier(0);
    }
    int tswp = s0; s0 = s1; s1 = s2; s2 = tswp;
  }
#undef STAGE

  // epilogue: reduce l across the 4 lanes sharing each q, write ctx (B,S,D) bf16
  const int b = bh >> 4, h = bh & 15;
#pragma unroll
  for (int g = 0; g < 2; ++g) {
    float lt = l_part[g];
    lt += __shfl_xor(lt, 16);
    lt += __shfl_xor(lt, 32);
#pragma unroll
    for (int r = 0; r < 4; ++r) {
      float li = __shfl(lt, (l & 48) | (lk * 4 + r));
      float inv = 1.0f / li;
      int q = gb0 + g * 16 + lk * 4 + r;
#pragma unroll
      for (int nj = 0; nj < 4; ++nj)
        ctx[((size_t)b * 2048 + q) * 1024 + h * 64 + nj * 16 + lm] = f2b(accO[g][nj][r] * inv);
    }
  }
}

// ---------- launch ----------
extern "C" void kernel_launch(void* const* d_in, const int* in_sizes, int n_in,
                              void* d_out, int out_size, void* d_ws, size_t ws_size,
                              hipStream_t stream) {
  (void)in_sizes; (void)n_in; (void)out_size; (void)ws_size;
  const float* x      = (const float*)d_in[0];
  const float* Wq     = (const float*)d_in[1];
  const float* Wk     = (const float*)d_in[2];
  const float* Wv     = (const float*)d_in[3];
  const float* in_w   = (const float*)d_in[4];
  const float* in_b   = (const float*)d_in[5];
  const float* out_w  = (const float*)d_in[6];
  const float* out_b  = (const float*)d_in[7];
  const float* proj_w = (const float*)d_in[8];
  const float* proj_b = (const float*)d_in[9];
  float* out = (float*)d_out;

  char* ws = (char*)d_ws;
  const size_t MB = 1ull << 20;
  // lifetime-overlapped layout (72 MB + 4 KB total):
  u16* xb   = (u16*)(ws);                    // 16MB; dead after QKV GEMM -> reused as ctx
  u16* ctx  = xb;
  u16* Qh   = (u16*)(ws + 16 * MB);          // 16MB
  u16* Kh   = (u16*)(ws + 32 * MB);          // 16MB; first 6MB doubles as in_w bf16 (prep only)
  u16* Vh   = (u16*)(ws + 48 * MB);          // 16MB; first 8MB = tmpT, +2MB = proj_w bf16 (prep only)
  u16* inwb = Kh;
  u16* tmpT = Vh;
  u16* pwb  = (u16*)(ws + 48 * MB + 8 * MB);
  u16* Wc   = (u16*)(ws + 64 * MB);          // 6MB combined QKV weights
  u16* W2   = (u16*)(ws + 70 * MB);          // 2MB combined output weights
  float* b2 = (float*)(ws + 72 * MB);        // 4KB combined output bias

  f32_to_bf16_k<<<4096, 256, 0, stream>>>(x, xb, 8388608);
  f32_to_bf16_k<<<1536, 256, 0, stream>>>(in_w, inwb, 3145728);
  f32_to_bf16_k<<<512, 256, 0, stream>>>(proj_w, pwb, 1048576);

  TransArgs ta;
  ta.in[0] = Wq; ta.in[1] = Wk; ta.in[2] = Wv; ta.in[3] = out_w;
  for (int z = 0; z < 4; ++z) ta.out[z] = tmpT + (size_t)z * 1048576;
  transpose4_k<<<dim3(16, 16, 4), 256, 0, stream>>>(ta);

  CombArgs ca;
  ca.A[0] = inwb; ca.A[1] = inwb + 1048576; ca.A[2] = inwb + 2097152; ca.A[3] = pwb;
  for (int z = 0; z < 4; ++z) ca.Bt[z] = tmpT + (size_t)z * 1048576;
  ca.C[0] = Wc; ca.C[1] = Wc + 1048576; ca.C[2] = Wc + 2097152; ca.C[3] = W2;
  gemm_combine_k<<<dim3(8, 8, 4), 256, 0, stream>>>(ca);

  make_b2_k<<<1024, 256, 0, stream>>>(proj_w, out_b, proj_b, b2);

  gemm_qkv_k<<<dim3(64, 24), 256, 0, stream>>>(xb, Wc, in_b, Qh, Kh, Vh);
  attn_k<<<512, 512, 0, stream>>>(Qh, Kh, Vh, ctx);
  gemm_final_k<<<dim3(64, 8), 256, 0, stream>>>(ctx, W2, b2, x, out);
}

// Round 8
// 274.569 us; speedup vs baseline: 1.5296x; 1.0429x over previous
//
#include <hip/hip_runtime.h>
#include <stdint.h>

typedef unsigned short u16;
typedef __attribute__((ext_vector_type(8))) short bfx8;   // 8 bf16 = 4 VGPR (MFMA A/B frag)
typedef __attribute__((ext_vector_type(4))) float fx4;    // 16x16 MFMA C/D frag
typedef __attribute__((ext_vector_type(16))) float fx16;  // 32x32 MFMA C/D frag

// ---------- helpers ----------
static __device__ __forceinline__ u16 f2b(float f) {
  union { float f; uint32_t u; } v; v.f = f;
  uint32_t r = v.u + 0x7fffu + ((v.u >> 16) & 1u);   // RNE
  return (u16)(r >> 16);
}

static __device__ __forceinline__ uint32_t cvtpk(float lo, float hi) {
  uint32_t r;
  asm("v_cvt_pk_bf16_f32 %0, %1, %2" : "=v"(r) : "v"(lo), "v"(hi));
  return r;
}

static __device__ __forceinline__ float ex2(float x) {   // raw v_exp_f32 (2^x)
  float r;
  asm("v_exp_f32 %0, %1" : "=v"(r) : "v"(x));
  return r;
}

static __device__ __forceinline__ void gload16(const void* g, void* lds) {
  __builtin_amdgcn_global_load_lds((const __attribute__((address_space(1))) uint32_t*)g,
                                   (__attribute__((address_space(3))) uint32_t*)lds,
                                   16, 0, 0);
}

// ---------- f32 -> bf16 convert (8 elems/thread, vectorized) ----------
__global__ __launch_bounds__(256) void f32_to_bf16_k(const float* __restrict__ in,
                                                     u16* __restrict__ out, int n) {
  int i = (blockIdx.x * 256 + threadIdx.x) * 8;
  if (i >= n) return;
  float4 a = *(const float4*)(in + i);
  float4 b = *(const float4*)(in + i + 4);
  bfx8 o;
  o[0]=(short)f2b(a.x); o[1]=(short)f2b(a.y); o[2]=(short)f2b(a.z); o[3]=(short)f2b(a.w);
  o[4]=(short)f2b(b.x); o[5]=(short)f2b(b.y); o[6]=(short)f2b(b.z); o[7]=(short)f2b(b.w);
  *(bfx8*)(out + i) = o;
}

// ---------- 1024x1024 f32 transpose -> bf16 (4 matrices batched in z) ----------
struct TransArgs { const float* in[4]; u16* out[4]; };
__global__ __launch_bounds__(256) void transpose4_k(TransArgs ta) {
  const float* in = ta.in[blockIdx.z];
  u16* out = ta.out[blockIdx.z];
  __shared__ u16 t[64][65];
  const int bx = blockIdx.x * 64, by = blockIdx.y * 64;
  const int tid = threadIdx.x;
#pragma unroll
  for (int i = 0; i < 16; ++i) {
    int idx = tid + i * 256; int r = idx >> 6, c = idx & 63;
    t[c][r] = f2b(in[(size_t)(by + r) * 1024 + bx + c]);
  }
  __syncthreads();
#pragma unroll
  for (int i = 0; i < 16; ++i) {
    int idx = tid + i * 256; int r = idx >> 6, c = idx & 63;
    out[(size_t)(bx + r) * 1024 + by + c] = t[r][c];
  }
}

// ---------- b2[f] = proj_b[f] + sum_e proj_w[f][e]*out_b[e] ----------
__global__ __launch_bounds__(256) void make_b2_k(const float* __restrict__ pw,
                                                 const float* __restrict__ ob,
                                                 const float* __restrict__ pb,
                                                 float* __restrict__ b2) {
  const int f = blockIdx.x, tid = threadIdx.x;
  float s = 0.f;
  for (int e = tid; e < 1024; e += 256) s += pw[(size_t)f * 1024 + e] * ob[e];
#pragma unroll
  for (int d = 1; d < 64; d <<= 1) s += __shfl_xor(s, d);
  __shared__ float red[4];
  if ((tid & 63) == 0) red[tid >> 6] = s;
  __syncthreads();
  if (tid == 0) b2[f] = red[0] + red[1] + red[2] + red[3] + pb[f];
}

// ---------- GEMM core: C = A(MxK) * Bt(NxK)^T, 128x128 tile, BK=64, 4 waves ----------
static __device__ __forceinline__ void gemm_core(const u16* __restrict__ A,
                                                 const u16* __restrict__ Bt,
                                                 int K, int bm, int bn,
                                                 u16* As, u16* Bs, fx4 (&acc)[4][4]) {
  const int tid = threadIdx.x, w = tid >> 6, l = tid & 63, lm = l & 15, lk = l >> 4;
  const int wm = w >> 1, wn = w & 1;
  const int nkt = K >> 6;
  for (int kt = 0; kt < nkt; ++kt) {
#pragma unroll
    for (int i = 0; i < 4; ++i) {
      int off = i * 4096 + w * 1024;         // wave-uniform LDS byte base
      int loff = off + l * 16;               // this lane's byte
      int row = loff >> 7, cb = loff & 127;  // tile row, byte-in-row (BK*2=128B rows)
      gload16((const char*)A + ((size_t)(bm * 128 + row) * K + kt * 64) * 2 + cb,
              (char*)As + off);
      gload16((const char*)Bt + ((size_t)(bn * 128 + row) * K + kt * 64) * 2 + cb,
              (char*)Bs + off);
    }
    __syncthreads();
#pragma unroll
    for (int kk = 0; kk < 2; ++kk) {
      bfx8 a[4], b[4];
#pragma unroll
      for (int mi = 0; mi < 4; ++mi)
        a[mi] = *(const bfx8*)((const char*)As + (wm * 64 + mi * 16 + lm) * 128 + lk * 16 + kk * 64);
#pragma unroll
      for (int nj = 0; nj < 4; ++nj)
        b[nj] = *(const bfx8*)((const char*)Bs + (wn * 64 + nj * 16 + lm) * 128 + lk * 16 + kk * 64);
#pragma unroll
      for (int mi = 0; mi < 4; ++mi)
#pragma unroll
        for (int nj = 0; nj < 4; ++nj)
          acc[mi][nj] = __builtin_amdgcn_mfma_f32_16x16x32_bf16(a[mi], b[nj], acc[mi][nj], 0, 0, 0);
    }
    __syncthreads();
  }
}

// ---------- combine GEMMs (4 batched in z): C[f][d] = sum_e A[f][e]*Bt[d][e], bf16 out ----------
struct CombArgs { const u16* A[4]; const u16* Bt[4]; u16* C[4]; };
__global__ __launch_bounds__(256) void gemm_combine_k(CombArgs ca) {
  const int z = blockIdx.z;
  __shared__ u16 As[8192], Bs[8192];
  fx4 acc[4][4];
#pragma unroll
  for (int mi = 0; mi < 4; ++mi)
#pragma unroll
    for (int nj = 0; nj < 4; ++nj) acc[mi][nj] = 0.f;
  gemm_core(ca.A[z], ca.Bt[z], 1024, blockIdx.x, blockIdx.y, As, Bs, acc);
  const int tid = threadIdx.x, w = tid >> 6, l = tid & 63, lm = l & 15, lk = l >> 4;
  const int wm = w >> 1, wn = w & 1;
  u16* C = ca.C[z];
#pragma unroll
  for (int mi = 0; mi < 4; ++mi)
#pragma unroll
    for (int nj = 0; nj < 4; ++nj)
#pragma unroll
      for (int r = 0; r < 4; ++r) {
        int m = blockIdx.x * 128 + wm * 64 + mi * 16 + lk * 4 + r;
        int n = blockIdx.y * 128 + wn * 64 + nj * 16 + lm;
        C[(size_t)m * 1024 + n] = f2b(acc[mi][nj][r]);
      }
}

// ---------- QKV GEMM: [8192x1024]x[3072x1024]^T + in_b ----------
// Q -> (B,H,S,64) plain; K -> (B,H,S,64) with hd XOR-swizzled (attn LDS swizzle baked in);
// V -> per-(bh,ktile) TRANSPOSED tile Vt[64 d][64 k], row-XOR-swizzled (same pattern as K).
__global__ __launch_bounds__(256) void gemm_qkv_k(const u16* __restrict__ xb,
                                                  const u16* __restrict__ Wc,
                                                  const float* __restrict__ bias,
                                                  u16* __restrict__ Qh, u16* __restrict__ Kh,
                                                  u16* __restrict__ Vh) {
  __shared__ u16 As[8192], Bs[8192];
  fx4 acc[4][4];
#pragma unroll
  for (int mi = 0; mi < 4; ++mi)
#pragma unroll
    for (int nj = 0; nj < 4; ++nj) acc[mi][nj] = 0.f;
  gemm_core(xb, Wc, 1024, blockIdx.x, blockIdx.y, As, Bs, acc);
  const int tid = threadIdx.x, w = tid >> 6, l = tid & 63, lm = l & 15, lk = l >> 4;
  const int wm = w >> 1, wn = w & 1;
  const int t = (blockIdx.y * 128) >> 10;                    // tensor select (tile-uniform)
  u16* dst = (t == 0) ? Qh : ((t == 1) ? Kh : Vh);
#pragma unroll
  for (int mi = 0; mi < 4; ++mi)
#pragma unroll
    for (int nj = 0; nj < 4; ++nj)
#pragma unroll
      for (int r = 0; r < 4; ++r) {
        int m = blockIdx.x * 128 + wm * 64 + mi * 16 + lk * 4 + r;
        int n = blockIdx.y * 128 + wn * 64 + nj * 16 + lm;
        float v = acc[mi][nj][r] + bias[n];
        int f = n & 1023, h = f >> 6, hd = f & 63, b = m >> 11, s = m & 2047;
        size_t hb = ((size_t)(b * 16 + h)) * 131072;   // 2048*64
        size_t idx;
        if (t == 2) {
          int sl = s & 63, st = s >> 6;                // Vt[d=hd][k=sl], row-swizzled
          idx = hb + (size_t)st * 4096 + (size_t)(hd * 64 + (sl ^ ((hd & 7) << 3)));
        } else if (t == 1) {
          idx = hb + (size_t)s * 64 + (hd ^ ((s & 7) << 3));
        } else {
          idx = hb + (size_t)s * 64 + hd;
        }
        dst[idx] = f2b(v);
      }
}

// ---------- final GEMM: ctx[8192x1024] x W2[1024x1024]^T + b2 + x, f32 out ----------
__global__ __launch_bounds__(256) void gemm_final_k(const u16* __restrict__ ctx,
                                                    const u16* __restrict__ W2,
                                                    const float* __restrict__ b2,
                                                    const float* __restrict__ x,
                                                    float* __restrict__ out) {
  __shared__ u16 As[8192], Bs[8192];
  fx4 acc[4][4];
#pragma unroll
  for (int mi = 0; mi < 4; ++mi)
#pragma unroll
    for (int nj = 0; nj < 4; ++nj) acc[mi][nj] = 0.f;
  gemm_core(ctx, W2, 1024, blockIdx.x, blockIdx.y, As, Bs, acc);
  const int tid = threadIdx.x, w = tid >> 6, l = tid & 63, lm = l & 15, lk = l >> 4;
  const int wm = w >> 1, wn = w & 1;
#pragma unroll
  for (int mi = 0; mi < 4; ++mi)
#pragma unroll
    for (int nj = 0; nj < 4; ++nj)
#pragma unroll
      for (int r = 0; r < 4; ++r) {
        int m = blockIdx.x * 128 + wm * 64 + mi * 16 + lk * 4 + r;
        int n = blockIdx.y * 128 + wn * 64 + nj * 16 + lm;
        size_t idx = (size_t)m * 1024 + n;
        out[idx] = acc[mi][nj][r] + b2[n] + x[idx];
      }
}

// ---------- fused attention, 32x32-MFMA path ----------
// scores = QK^T/8 + tril(1.0), softmax over FULL row (log2 domain), ctx = P*V.
// 4 waves (256 thr), QBLK=128: wave owns 32 q rows; lane owns q=l&31 (key-half h=l>>5).
// QK^T swapped via mfma_32x32x16(K,Q): softmax lane-local; all cross-lane movement
// via __shfl_xor(...,32) (known semantics) — NO permlane asm in this version.
// P -> PV A-frags in-register: cvt_pk + xor-32 exchange + half-uniform selects.
__global__ __launch_bounds__(256, 4) void attn_k(const u16* __restrict__ Qh,
                                                 const u16* __restrict__ Kh,
                                                 const u16* __restrict__ Vh,
                                                 u16* __restrict__ ctx) {
  // XCD-chunked swizzle: 1024 blocks / 8 XCDs = 128 contiguous work items (8 bh) per XCD.
  const int bl = blockIdx.x;
  const int wk = (bl & 7) * 128 + (bl >> 3);
  const int bh = wk >> 4, qt = wk & 15;
  const int tid = threadIdx.x, w = tid >> 6, l = tid & 63;
  const int ql = l & 31, h = l >> 5;
  __shared__ __align__(16) u16 Ks[2][4096];
  __shared__ __align__(16) u16 Vs[2][4096];

  const float SC = 0.18033688011112042f;    // 0.125 * log2(e)
  const float MA = 1.4426950408889634f;     // 1.0  * log2(e)
  const float THR = 11.541560327111708f;    // 8.0  * log2(e)

  const size_t base = (size_t)bh * 131072;
  const int qb = qt * 128 + w * 32;         // wave q-base
  const int q = qb + ql;                    // lane's q row
  // Q B-frag: lane holds Q[q][d = ks*16 + 8h + e], ks=0..3
  bfx8 qf[4];
  {
    const u16* qp = Qh + base + (size_t)q * 64 + 8 * h;
    qf[0] = *(const bfx8*)(qp);
    qf[1] = *(const bfx8*)(qp + 16);
    qf[2] = *(const bfx8*)(qp + 32);
    qf[3] = *(const bfx8*)(qp + 48);
  }
  float m_run = -1024.f, l_part = 0.f;      // finite init; l_part = this half's partial
  fx16 accO[2];
  accO[0] = 0.f; accO[1] = 0.f;

  const char* Kg = (const char*)(Kh + base);
  const char* Vg = (const char*)(Vh + base);
  const int o = tid * 16;                   // 256 thr x 16B = half a tile per instr
  const int sw8 = (ql & 7) << 4;

#define STAGE(t, s)                                                        \
  {                                                                        \
    gload16(Kg + (size_t)(t) * 8192 + o,        (char*)Ks[s] + o);         \
    gload16(Kg + (size_t)(t) * 8192 + o + 4096, (char*)Ks[s] + o + 4096);  \
    gload16(Vg + (size_t)(t) * 8192 + o,        (char*)Vs[s] + o);         \
    gload16(Vg + (size_t)(t) * 8192 + o + 4096, (char*)Vs[s] + o + 4096);  \
  }

  STAGE(0, 0);
  asm volatile("s_waitcnt vmcnt(0)" ::: "memory");
  __builtin_amdgcn_s_barrier();
  __builtin_amdgcn_sched_barrier(0);

  int cur = 0;
  for (int kt = 0; kt < 32; ++kt) {
    if (kt + 1 < 32) STAGE(kt + 1, cur ^ 1);   // issue early; lands before end-of-iter wait
    __builtin_amdgcn_sched_barrier(0);

    const char* Kc = (const char*)Ks[cur];
    const char* Vc = (const char*)Vs[cur];

    // QK^T (swapped): S[q=qb+ql][key]; lane col = ql, key rows = kb*32 + (r&3)+8*(r>>2)+4h
    fx16 sS[2];
    sS[0] = 0.f; sS[1] = 0.f;
    __builtin_amdgcn_s_setprio(1);
#pragma unroll
    for (int ks = 0; ks < 4; ++ks) {
      bfx8 kf0 = *(const bfx8*)(Kc + (0 * 32 + ql) * 128 + (((ks << 5) | (h << 4)) ^ sw8));
      bfx8 kf1 = *(const bfx8*)(Kc + (1 * 32 + ql) * 128 + (((ks << 5) | (h << 4)) ^ sw8));
      sS[0] = __builtin_amdgcn_mfma_f32_32x32x16_bf16(kf0, qf[ks], sS[0], 0, 0, 0);
      sS[1] = __builtin_amdgcn_mfma_f32_32x32x16_bf16(kf1, qf[ks], sS[1], 0, 0, 0);
    }
    __builtin_amdgcn_s_setprio(0);

    // scale to log2 domain + additive tril mask, bias-folded (cO = -m_run)
    const int dk = kt - (qb >> 6);
    {
      float cO = -m_run, cI = cO + MA;
      if (dk < 0) {
#pragma unroll
        for (int r = 0; r < 16; ++r) {
          sS[0][r] = fmaf(sS[0][r], SC, cI);
          sS[1][r] = fmaf(sS[1][r], SC, cI);
        }
      } else if (dk > 0) {
#pragma unroll
        for (int r = 0; r < 16; ++r) {
          sS[0][r] = fmaf(sS[0][r], SC, cO);
          sS[1][r] = fmaf(sS[1][r], SC, cO);
        }
      } else {
#pragma unroll
        for (int kb = 0; kb < 2; ++kb)
#pragma unroll
          for (int r = 0; r < 16; ++r) {
            int key = kt * 64 + kb * 32 + (r & 3) + 8 * (r >> 2) + 4 * h;
            sS[kb][r] = fmaf(sS[kb][r], SC, (key <= q) ? cI : cO);
          }
      }
    }
    // local max over this lane's 32 scores; row-combine with the partner half lane
    float mx;
    {
      float m0 = fmaxf(fmaxf(sS[0][0], sS[0][1]), fmaxf(sS[0][2], sS[0][3]));
      float m1 = fmaxf(fmaxf(sS[0][4], sS[0][5]), fmaxf(sS[0][6], sS[0][7]));
      float m2 = fmaxf(fmaxf(sS[0][8], sS[0][9]), fmaxf(sS[0][10], sS[0][11]));
      float m3 = fmaxf(fmaxf(sS[0][12], sS[0][13]), fmaxf(sS[0][14], sS[0][15]));
      float m4 = fmaxf(fmaxf(sS[1][0], sS[1][1]), fmaxf(sS[1][2], sS[1][3]));
      float m5 = fmaxf(fmaxf(sS[1][4], sS[1][5]), fmaxf(sS[1][6], sS[1][7]));
      float m6 = fmaxf(fmaxf(sS[1][8], sS[1][9]), fmaxf(sS[1][10], sS[1][11]));
      float m7 = fmaxf(fmaxf(sS[1][12], sS[1][13]), fmaxf(sS[1][14], sS[1][15]));
      mx = fmaxf(fmaxf(fmaxf(m0, m1), fmaxf(m2, m3)), fmaxf(fmaxf(m4, m5), fmaxf(m6, m7)));
    }
    float full = fmaxf(mx, __shfl_xor(mx, 32));   // row max over this tile's 64 keys
    if (!__all(full <= THR)) {                    // rare rescale (defer-max)
      float d = fmaxf(full, 0.f);
      float corr = ex2(-d);
      m_run += d;
      l_part *= corr;
#pragma unroll
      for (int r = 0; r < 16; ++r) {
        int rq = (r & 3) + 8 * (r >> 2) + 4 * h;
        float cr = __shfl(corr, (l & 32) | rq);
        accO[0][r] *= cr;
        accO[1][r] *= cr;
        sS[0][r] -= d;
        sS[1][r] -= d;
      }
    }
    // exp + partial row-sum (this half only; pair-reduced in epilogue)
    fx16 tt;
#pragma unroll
    for (int r = 0; r < 16; ++r) {
      sS[0][r] = ex2(sS[0][r]);
      sS[1][r] = ex2(sS[1][r]);
      tt[r] = sS[0][r] + sS[1][r];
    }
    {
      float ls0 = tt[0] + tt[8],  ls1 = tt[1] + tt[9];
      float ls2 = tt[2] + tt[10], ls3 = tt[3] + tt[11];
      float ls4 = tt[4] + tt[12], ls5 = tt[5] + tt[13];
      float ls6 = tt[6] + tt[14], ls7 = tt[7] + tt[15];
      l_part += ((ls0 + ls4) + (ls1 + ls5)) + ((ls2 + ls6) + (ls3 + ls7));
    }
    // P -> PV A-frags: cvt_pk pairs, then xor-32 exchange (known semantics).
    // pw[kb*4+gg] at lane (ql,h_src) holds keys kb*32 + 8*gg + 4*h_src + {0..3}.
    // Dest lane (ql,h), pa[ks] needs keys 16ks+8h+{0..7}:
    //   low 4 from lane (ql,0)'s pw[2ks+h]; high 4 from lane (ql,1)'s pw[2ks+h].
    uint32_t pw[8][2];
#pragma unroll
    for (int kb = 0; kb < 2; ++kb)
#pragma unroll
      for (int gg = 0; gg < 4; ++gg) {
        pw[kb * 4 + gg][0] = cvtpk(sS[kb][4 * gg + 0], sS[kb][4 * gg + 1]);
        pw[kb * 4 + gg][1] = cvtpk(sS[kb][4 * gg + 2], sS[kb][4 * gg + 3]);
      }

    // PV: O[q][d] += P[q][k] V[k][d]; B-frag from transposed V tile (plain b128)
    __builtin_amdgcn_s_setprio(1);
#pragma unroll
    for (int ks = 0; ks < 4; ++ks) {
      union { uint32_t u[4]; bfx8 v; } pa;
#pragma unroll
      for (int p = 0; p < 2; ++p) {
        // h=0 lane contributes pw[2ks+1] (partner needs it), receives partner's pw[2ks].
        // h=1 lane contributes pw[2ks],   receives partner's pw[2ks+1].
        uint32_t contrib = h ? pw[2 * ks][p] : pw[2 * ks + 1][p];
        uint32_t rcv = __shfl_xor(contrib, 32);
        pa.u[p]     = h ? rcv : pw[2 * ks][p];       // keys 16ks+8h+{0..3}
        pa.u[2 + p] = h ? pw[2 * ks + 1][p] : rcv;   // keys 16ks+8h+{4..7}
      }
      bfx8 vf0 = *(const bfx8*)(Vc + (0 * 32 + ql) * 128 + (((ks << 5) | (h << 4)) ^ sw8));
      bfx8 vf1 = *(const bfx8*)(Vc + (1 * 32 + ql) * 128 + (((ks << 5) | (h << 4)) ^ sw8));
      accO[0] = __builtin_amdgcn_mfma_f32_32x32x16_bf16(pa.v, vf0, accO[0], 0, 0, 0);
      accO[1] = __builtin_amdgcn_mfma_f32_32x32x16_bf16(pa.v, vf1, accO[1], 0, 0, 0);
    }
    __builtin_amdgcn_s_setprio(0);

    asm volatile("s_waitcnt vmcnt(0)" ::: "memory");   // next tile landed (in flight all iter)
    __builtin_amdgcn_s_barrier();
    __builtin_amdgcn_sched_barrier(0);
    cur ^= 1;
  }
#undef STAGE

  // epilogue: pair-reduce l, write ctx (B,S,D) bf16
  float inv = 1.0f / (l_part + __shfl_xor(l_part, 32));   // full row sum for q=ql
  const int b = bh >> 4, hcol = bh & 15;
#pragma unroll
  for (int r = 0; r < 16; ++r) {
    int rq = (r & 3) + 8 * (r >> 2) + 4 * h;
    float invq = __shfl(inv, (l & 32) | rq);
    size_t rowb = ((size_t)b * 2048 + (qb + rq)) * 1024 + hcol * 64 + ql;
    ctx[rowb]      = f2b(accO[0][r] * invq);   // d = ql
    ctx[rowb + 32] = f2b(accO[1][r] * invq);   // d = 32 + ql
  }
}

// ---------- launch ----------
extern "C" void kernel_launch(void* const* d_in, const int* in_sizes, int n_in,
                              void* d_out, int out_size, void* d_ws, size_t ws_size,
                              hipStream_t stream) {
  (void)in_sizes; (void)n_in; (void)out_size; (void)ws_size;
  const float* x      = (const float*)d_in[0];
  const float* Wq     = (const float*)d_in[1];
  const float* Wk     = (const float*)d_in[2];
  const float* Wv     = (const float*)d_in[3];
  const float* in_w   = (const float*)d_in[4];
  const float* in_b   = (const float*)d_in[5];
  const float* out_w  = (const float*)d_in[6];
  const float* out_b  = (const float*)d_in[7];
  const float* proj_w = (const float*)d_in[8];
  const float* proj_b = (const float*)d_in[9];
  float* out = (float*)d_out;

  char* ws = (char*)d_ws;
  const size_t MB = 1ull << 20;
  // lifetime-overlapped layout (72 MB + 4 KB total):
  u16* xb   = (u16*)(ws);                    // 16MB; dead after QKV GEMM -> reused as ctx
  u16* ctx  = xb;
  u16* Qh   = (u16*)(ws + 16 * MB);          // 16MB
  u16* Kh   = (u16*)(ws + 32 * MB);          // 16MB; first 6MB doubles as in_w bf16 (prep only)
  u16* Vh   = (u16*)(ws + 48 * MB);          // 16MB; first 8MB = tmpT, +2MB = proj_w bf16 (prep only)
  u16* inwb = Kh;
  u16* tmpT = Vh;
  u16* pwb  = (u16*)(ws + 48 * MB + 8 * MB);
  u16* Wc   = (u16*)(ws + 64 * MB);          // 6MB combined QKV weights
  u16* W2   = (u16*)(ws + 70 * MB);          // 2MB combined output weights
  float* b2 = (float*)(ws + 72 * MB);        // 4KB combined output bias

  f32_to_bf16_k<<<4096, 256, 0, stream>>>(x, xb, 8388608);
  f32_to_bf16_k<<<1536, 256, 0, stream>>>(in_w, inwb, 3145728);
  f32_to_bf16_k<<<512, 256, 0, stream>>>(proj_w, pwb, 1048576);

  TransArgs ta;
  ta.in[0] = Wq; ta.in[1] = Wk; ta.in[2] = Wv; ta.in[3] = out_w;
  for (int z = 0; z < 4; ++z) ta.out[z] = tmpT + (size_t)z * 1048576;
  transpose4_k<<<dim3(16, 16, 4), 256, 0, stream>>>(ta);

  CombArgs ca;
  ca.A[0] = inwb; ca.A[1] = inwb + 1048576; ca.A[2] = inwb + 2097152; ca.A[3] = pwb;
  for (int z = 0; z < 4; ++z) ca.Bt[z] = tmpT + (size_t)z * 1048576;
  ca.C[0] = Wc; ca.C[1] = Wc + 1048576; ca.C[2] = Wc + 2097152; ca.C[3] = W2;
  gemm_combine_k<<<dim3(8, 8, 4), 256, 0, stream>>>(ca);

  make_b2_k<<<1024, 256, 0, stream>>>(proj_w, out_b, proj_b, b2);

  gemm_qkv_k<<<dim3(64, 24), 256, 0, stream>>>(xb, Wc, in_b, Qh, Kh, Vh);
  attn_k<<<1024, 256, 0, stream>>>(Qh, Kh, Vh, ctx);
  gemm_final_k<<<dim3(64, 8), 256, 0, stream>>>(ctx, W2, b2, x, out);
}